// Round 3
// baseline (1877.332 us; speedup 1.0000x reference)
//
#include <hip/hip_runtime.h>
#include <cstdint>
#include <cstddef>

// ---------------- constants ----------------
#define MAXSEL 160
static constexpr int S    = 4096;
static constexpr int H    = 1024;
static constexpr int DH   = 64;
static constexpr int NB   = 128;   // seq blocks (4096/32)
static constexpr int MBH  = 32;    // b*h = 2*16
static constexpr int M8   = 8192;  // 2*4096 rows
static constexpr int N3   = 3072;  // q|k|v features

typedef _Float16 half8 __attribute__((ext_vector_type(8)));
typedef _Float16 half4v __attribute__((ext_vector_type(4)));
typedef float floatx4 __attribute__((ext_vector_type(4)));

__device__ __forceinline__ void load_lds16(const void* g, void* l) {
  __builtin_amdgcn_global_load_lds((const __attribute__((address_space(1))) unsigned int*)g,
                                   (__attribute__((address_space(3))) unsigned int*)l,
                                   16, 0, 0);
}

// ---------------- fused prep: hbar + h16 cast (blocks<256) | weight cast (rest) -------
__global__ __launch_bounds__(256) void k_prep(const float* __restrict__ hidden,
                                              const float* __restrict__ am,
                                              const float* __restrict__ wq,
                                              const float* __restrict__ wk,
                                              const float* __restrict__ wv,
                                              _Float16* __restrict__ h16,
                                              _Float16* __restrict__ w16,
                                              _Float16* __restrict__ wlo,
                                              _Float16* __restrict__ hb_hi,
                                              _Float16* __restrict__ hb_lo,
                                              float* __restrict__ tcv) {
  const int blk_id = blockIdx.x;
  if (blk_id < 256) {
    int b2 = blk_id >> 7, blk = blk_id & 127;
    int c = threadIdx.x * 4;
    float4 s0 = make_float4(0.f, 0.f, 0.f, 0.f);
    float4 s1 = make_float4(0.f, 0.f, 0.f, 0.f);
    for (int i = 0; i < 32; ++i) {
      int pos = blk * 32 + i;
      size_t base = ((size_t)b2 * 4096 + pos) * 1024 + c;
      const float4 x = *(const float4*)&hidden[base];
      half4v h;
      h[0] = (_Float16)x.x; h[1] = (_Float16)x.y;
      h[2] = (_Float16)x.z; h[3] = (_Float16)x.w;
      *(half4v*)&h16[base] = h;
      float m0 = 1.f + am[pos] * 1e-4f;
      float m1 = 1.f + am[4096 + pos] * 1e-4f;
      s0.x += m0 * x.x; s0.y += m0 * x.y; s0.z += m0 * x.z; s0.w += m0 * x.w;
      s1.x += m1 * x.x; s1.y += m1 * x.y; s1.z += m1 * x.z; s1.w += m1 * x.w;
    }
    size_t row0 = (size_t)(b2 * 2 + 0) * 128 + blk;
    size_t row1 = (size_t)(b2 * 2 + 1) * 128 + blk;
    half4v hi, lo;
    hi[0]=(_Float16)s0.x; lo[0]=(_Float16)(s0.x-(float)hi[0]);
    hi[1]=(_Float16)s0.y; lo[1]=(_Float16)(s0.y-(float)hi[1]);
    hi[2]=(_Float16)s0.z; lo[2]=(_Float16)(s0.z-(float)hi[2]);
    hi[3]=(_Float16)s0.w; lo[3]=(_Float16)(s0.w-(float)hi[3]);
    *(half4v*)&hb_hi[row0 * 1024 + c] = hi;
    *(half4v*)&hb_lo[row0 * 1024 + c] = lo;
    hi[0]=(_Float16)s1.x; lo[0]=(_Float16)(s1.x-(float)hi[0]);
    hi[1]=(_Float16)s1.y; lo[1]=(_Float16)(s1.y-(float)hi[1]);
    hi[2]=(_Float16)s1.z; lo[2]=(_Float16)(s1.z-(float)hi[2]);
    hi[3]=(_Float16)s1.w; lo[3]=(_Float16)(s1.w-(float)hi[3]);
    *(half4v*)&hb_hi[row1 * 1024 + c] = hi;
    *(half4v*)&hb_lo[row1 * 1024 + c] = lo;
    if (b2 == 0 && threadIdx.x == 0) {
      float t0 = 0.f, t1 = 0.f;
      for (int i = 0; i < 32; ++i) {
        int pos = blk * 32 + i;
        t0 += 1.f + am[pos] * 1e-4f;
        t1 += 1.f + am[4096 + pos] * 1e-4f;
      }
      tcv[blk] = t0; tcv[128 + blk] = t1;
    }
  } else {
    long j = (long)(blk_id - 256) * 256 + threadIdx.x;   // float4 index into weights
    const long NW4 = (long)H * H / 4;
    int which = (int)(j / NW4);
    long jj = j - (long)which * NW4;
    const float* src = which == 0 ? wq : (which == 1 ? wk : wv);
    float4 x = ((const float4*)src)[jj];
    half4v h;
    h[0] = (_Float16)x.x; h[1] = (_Float16)x.y;
    h[2] = (_Float16)x.z; h[3] = (_Float16)x.w;
    *(half4v*)&w16[j * 4] = h;
    if (which < 2) {
      half4v r;
      r[0] = (_Float16)(x.x - (float)h[0]);
      r[1] = (_Float16)(x.y - (float)h[1]);
      r[2] = (_Float16)(x.z - (float)h[2]);
      r[3] = (_Float16)(x.w - (float)h[3]);
      *(half4v*)&wlo[j * 4] = r;
    }
  }
}

// ---------------- main QKV projection: C(8192x3072) = A(8192x1024) @ W^T, fp16 MFMA ----
// XOR-swizzled LDS (conflict-free, R2-verified). V tiles write v16T (d-major) + vhat
// directly from accumulators; q/k tiles write [s][d] layout.
__global__ __launch_bounds__(256) void k_gemm_qkv(const _Float16* __restrict__ A,
                                                  const _Float16* __restrict__ B,
                                                  const float* __restrict__ bq,
                                                  const float* __restrict__ bk,
                                                  const float* __restrict__ bv,
                                                  const float* __restrict__ am,
                                                  const float* __restrict__ tcv,
                                                  _Float16* __restrict__ q16,
                                                  _Float16* __restrict__ k16,
                                                  _Float16* __restrict__ v16T,
                                                  float* __restrict__ vhat) {
  const int bx = blockIdx.x;           // N tile 0..23
  const int by = blockIdx.y;           // M tile 0..63
  const int tid = threadIdx.x;
  const int lane = tid & 63, wv = tid >> 6;
  const int wm = wv >> 1, wn = wv & 1;
  const int l15 = lane & 15, quad = lane >> 4;

  __shared__ _Float16 As[128 * 64];
  __shared__ _Float16 Bs[128 * 64];

  floatx4 acc[4][4] = {};

  const _Float16* Ag = A + (size_t)(by * 128) * 1024;
  const _Float16* Bg = B + (size_t)(bx * 128) * 1024;
  const int srow_l = lane >> 3;                              // 0..7
  const int scol   = (((lane & 7) ^ (srow_l & 7)) * 8);      // swizzled source chunk
  const int swz    = l15 & 7;

  for (int k0 = 0; k0 < 1024; k0 += 64) {
    __syncthreads();
#pragma unroll
    for (int i = 0; i < 4; ++i) {
      int rb = i * 32 + wv * 8;
      load_lds16(Ag + (size_t)(rb + srow_l) * 1024 + k0 + scol, &As[rb * 64]);
      load_lds16(Bg + (size_t)(rb + srow_l) * 1024 + k0 + scol, &Bs[rb * 64]);
    }
    __syncthreads();
#pragma unroll
    for (int ks = 0; ks < 2; ++ks) {
      const int kc = ks * 4;
      half8 a[4], b[4];
#pragma unroll
      for (int mt = 0; mt < 4; ++mt)
        a[mt] = *(const half8*)&As[(wm * 64 + mt * 16 + l15) * 64 + (((kc + quad) ^ swz) << 3)];
#pragma unroll
      for (int nt = 0; nt < 4; ++nt)
        b[nt] = *(const half8*)&Bs[(wn * 64 + nt * 16 + l15) * 64 + (((kc + quad) ^ swz) << 3)];
#pragma unroll
      for (int mt = 0; mt < 4; ++mt)
#pragma unroll
        for (int nt = 0; nt < 4; ++nt)
          acc[mt][nt] = __builtin_amdgcn_mfma_f32_16x16x32_f16(a[mt], b[nt], acc[mt][nt], 0, 0, 0);
    }
  }

  const int which = (bx * 128) >> 10;  // uniform per CTA: 0=q 1=k 2=v
  if (which == 2) {
    // ---- V epilogue: v16T (d-major) + vhat block means ----
    const int mrow0 = by * 128 + wm * 64;      // 64-aligned; never straddles 4096
    const int b2 = mrow0 >> 12;
    const int sbase = mrow0 & 4095;
    const int blkA = sbase >> 5;               // even block
    const int hh = ((bx * 128 + wn * 64) >> 6) & 15;
    const int m2 = hh & 1;
    const int mb = b2 * 16 + hh;
#pragma unroll
    for (int nt = 0; nt < 4; ++nt) {
      int oo = (bx * 128 + wn * 64 + nt * 16 + l15) & 1023;
      int dd = oo & 63;                        // = nt*16 + l15
      float bsv = bv[oo];
      float sA = 0.f, sB = 0.f;
#pragma unroll
      for (int mt = 0; mt < 4; ++mt) {
        half4v vv;
#pragma unroll
        for (int r = 0; r < 4; ++r) {
          int s = sbase + mt * 16 + quad * 4 + r;
          float mv = 1.f + am[m2 * 4096 + s] * 1e-4f;
          float v = (acc[mt][nt][r] + bsv) * mv;
          vv[r] = (_Float16)v;
          if (mt < 2) sA += v; else sB += v;
        }
        int s0 = sbase + mt * 16 + quad * 4;
        *(half4v*)&v16T[((size_t)(mb * 64 + dd)) * 4096 + s0] = vv;
      }
      sA += __shfl_xor(sA, 16); sA += __shfl_xor(sA, 32);
      sB += __shfl_xor(sB, 16); sB += __shfl_xor(sB, 32);
      if (quad == 0)
        vhat[((size_t)(mb * 128 + blkA)) * 64 + dd]     = sA / (tcv[m2 * 128 + blkA] + 1e-6f);
      else if (quad == 1)
        vhat[((size_t)(mb * 128 + blkA + 1)) * 64 + dd] = sB / (tcv[m2 * 128 + blkA + 1] + 1e-6f);
    }
  } else {
    const float* bias = which == 0 ? bq : bk;
    _Float16* dst = which == 0 ? q16 : k16;
#pragma unroll
    for (int nt = 0; nt < 4; ++nt) {
      int o  = bx * 128 + wn * 64 + nt * 16 + l15;
      int oo = o & 1023;
      int hh = oo >> 6, dd = oo & 63;
      int m2 = hh & 1;
      float bsv = bias[oo];
#pragma unroll
      for (int mt = 0; mt < 4; ++mt) {
#pragma unroll
        for (int r = 0; r < 4; ++r) {
          int srow = by * 128 + wm * 64 + mt * 16 + quad * 4 + r;
          int b2 = srow >> 12, s = srow & 4095;
          float mv = 1.f + am[m2 * 4096 + s] * 1e-4f;
          float v = (acc[mt][nt][r] + bsv) * mv;
          int mb = b2 * 16 + hh;
          dst[((size_t)mb * 4096 + s) * 64 + dd] = (_Float16)v;
        }
      }
    }
  }
}

// ---------------- fp16x3 GEMM (pre-split inputs): sideQK(512x2048) = hbar @ [wq;wk]^T --
__global__ __launch_bounds__(256) void k_side(const _Float16* __restrict__ Ahi,
                                              const _Float16* __restrict__ Alo,
                                              const _Float16* __restrict__ Bhi,
                                              const _Float16* __restrict__ Blo,
                                              float* __restrict__ sideQK) {
  const int bx = blockIdx.x;   // 0..31 (N/64)
  const int by = blockIdx.y;   // 0..7  (M/64)
  const int tid = threadIdx.x;
  const int lane = tid & 63, wv = tid >> 6;
  const int wm = wv >> 1, wn = wv & 1;
  const int l15 = lane & 15, quad = lane >> 4;

  __shared__ _Float16 sAhi[64*64], sAlo[64*64], sBhi[64*64], sBlo[64*64];
  floatx4 acc[2][2] = {};

  const int srow = lane >> 3;
  const int scol = (((lane & 7) ^ (srow & 7)) * 8);
  const int swz  = l15 & 7;
  const _Float16* src;
  _Float16* dst;
  if      (wv == 0) { src = Ahi + (size_t)(by * 64) * 1024; dst = sAhi; }
  else if (wv == 1) { src = Alo + (size_t)(by * 64) * 1024; dst = sAlo; }
  else if (wv == 2) { src = Bhi + (size_t)(bx * 64) * 1024; dst = sBhi; }
  else              { src = Blo + (size_t)(bx * 64) * 1024; dst = sBlo; }

  for (int k0 = 0; k0 < 1024; k0 += 64) {
    __syncthreads();
#pragma unroll
    for (int i = 0; i < 8; ++i)
      load_lds16(src + (size_t)(i * 8 + srow) * 1024 + k0 + scol, dst + i * 512);
    __syncthreads();
#pragma unroll
    for (int ks = 0; ks < 2; ++ks) {
      const int kc = ks * 4;
      half8 ah[2], al[2], bh[2], bl[2];
#pragma unroll
      for (int mt = 0; mt < 2; ++mt) {
        int off = (wm * 32 + mt * 16 + l15) * 64 + (((kc + quad) ^ swz) << 3);
        ah[mt] = *(const half8*)&sAhi[off];
        al[mt] = *(const half8*)&sAlo[off];
      }
#pragma unroll
      for (int nt = 0; nt < 2; ++nt) {
        int off = (wn * 32 + nt * 16 + l15) * 64 + (((kc + quad) ^ swz) << 3);
        bh[nt] = *(const half8*)&sBhi[off];
        bl[nt] = *(const half8*)&sBlo[off];
      }
#pragma unroll
      for (int mt = 0; mt < 2; ++mt)
#pragma unroll
        for (int nt = 0; nt < 2; ++nt) {
          acc[mt][nt] = __builtin_amdgcn_mfma_f32_16x16x32_f16(ah[mt], bh[nt], acc[mt][nt], 0, 0, 0);
          acc[mt][nt] = __builtin_amdgcn_mfma_f32_16x16x32_f16(ah[mt], bl[nt], acc[mt][nt], 0, 0, 0);
          acc[mt][nt] = __builtin_amdgcn_mfma_f32_16x16x32_f16(al[mt], bh[nt], acc[mt][nt], 0, 0, 0);
        }
    }
  }
#pragma unroll
  for (int mt = 0; mt < 2; ++mt)
#pragma unroll
    for (int nt = 0; nt < 2; ++nt)
#pragma unroll
      for (int rr = 0; rr < 4; ++rr) {
        int row = by * 64 + wm * 32 + mt * 16 + quad * 4 + rr;
        int col = bx * 64 + wn * 32 + nt * 16 + l15;
        sideQK[(size_t)row * 2048 + col] = acc[mt][nt][rr];
      }
}

// ---------------- low-resolution logits + row max (conflict-free, rotated d) ----------
__global__ __launch_bounds__(256) void k_lowlogit(const float* __restrict__ sideQK,
                                                  const float* __restrict__ tcv,
                                                  const float* __restrict__ bq,
                                                  const float* __restrict__ bk,
                                                  float* __restrict__ ll,
                                                  float* __restrict__ rmaxout) {
  const int mb = blockIdx.x;
  const int ib = blockIdx.y;       // 0..7 : rows ib*16..+16
  const int b2 = mb >> 4, m2 = mb & 1, hh = mb & 15;
  const int combo = b2 * 2 + m2;
  const int tid = threadIdx.x;
  __shared__ float Kh[128 * 64];
  __shared__ float Qh[16 * 64];
  __shared__ float tcL[128];

  if (tid < 128) tcL[tid] = tcv[m2 * 128 + tid];
  __syncthreads();
#pragma unroll
  for (int i = 0; i < 8; ++i) {
    int ci = tid + i * 256;
    int row = ci >> 4, c4 = (ci & 15) * 4;
    float tck = tcL[row];
    float den = 1.f / (tck + 1e-6f);
    float4 x  = *(const float4*)&sideQK[((size_t)combo * 128 + row) * 2048 + 1024 + hh * 64 + c4];
    float4 bb = *(const float4*)&bk[hh * 64 + c4];
    float4 o;
    o.x = (x.x + bb.x * tck) * den; o.y = (x.y + bb.y * tck) * den;
    o.z = (x.z + bb.z * tck) * den; o.w = (x.w + bb.w * tck) * den;
    *(float4*)&Kh[row * 64 + c4] = o;
  }
  {
    int row = tid >> 4, c4 = (tid & 15) * 4;
    int gi = ib * 16 + row;
    float tcq = tcL[gi];
    float den = 1.f / (tcq + 1e-6f);
    float4 x  = *(const float4*)&sideQK[((size_t)combo * 128 + gi) * 2048 + hh * 64 + c4];
    float4 bb = *(const float4*)&bq[hh * 64 + c4];
    float4 o;
    o.x = (x.x + bb.x * tcq) * den; o.y = (x.y + bb.y * tcq) * den;
    o.z = (x.z + bb.z * tcq) * den; o.w = (x.w + bb.w * tcq) * den;
    *(float4*)&Qh[row * 64 + c4] = o;
  }
  __syncthreads();

  const int il = tid >> 4, jg = tid & 15;
  const int i = ib * 16 + il;
  float tcq = tcL[i];
  float dots[8] = {};
#pragma unroll
  for (int dd = 0; dd < 16; ++dd) {
    int d4 = ((dd + tid) & 15) * 4;       // lane-rotated: conflict-free LDS columns
    float4 qv = *(const float4*)&Qh[il * 64 + d4];
#pragma unroll
    for (int jj = 0; jj < 8; ++jj) {
      float4 kv = *(const float4*)&Kh[(jg * 8 + jj) * 64 + d4];
      dots[jj] += qv.x * kv.x + qv.y * kv.y + qv.z * kv.z + qv.w * kv.w;
    }
  }
  float tmax = -1e30f;
#pragma unroll
  for (int jj = 0; jj < 8; ++jj) {
    int j = jg * 8 + jj;
    float raw = dots[jj] * 0.125f;
    tmax = fmaxf(tmax, raw);
    float pen = (tcq * tcL[j] < 0.5f) ? 10000.f : 0.f;
    ll[(size_t)mb * 16384 + (size_t)i * 128 + j] = raw - pen;
  }
#pragma unroll
  for (int mk = 1; mk < 16; mk <<= 1) tmax = fmaxf(tmax, __shfl_xor(tmax, mk));
  if (jg == 0) rmaxout[mb * 128 + i] = tmax;
}

// ---------------- exact top-512 threshold + selected-block buckets --------------------
__global__ __launch_bounds__(256) void k_topk(const float* __restrict__ ll,
                                              const float* __restrict__ rmax,
                                              float* __restrict__ thr,
                                              int* __restrict__ selcnt,
                                              int* __restrict__ selkb) {
  const int mb = blockIdx.x;
  const int t = threadIdx.x;
  const int wid = t >> 6;
  __shared__ int red2[2][4];

  unsigned code[64];
#pragma unroll
  for (int j = 0; j < 64; ++j) {
    int e = j * 256 + t;
    int i = e >> 7, jj = e & 127;
    float lrn = ll[(size_t)mb * 16384 + e] - rmax[mb * 128 + i];
    int di = i - jj;
    if (di <= 1 && di >= -1) lrn += 5000.f;
    unsigned b = __float_as_uint(lrn);
    code[j] = (b & 0x80000000u) ? ~b : (b | 0x80000000u);
  }

  unsigned lo = 0u, hi = 0xFFFFFFFFu;
  for (int it = 0; it < 32; ++it) {
    unsigned mid = lo + ((hi - lo) >> 1);
    int c = 0;
#pragma unroll
    for (int j = 0; j < 64; ++j) c += (code[j] >= mid) ? 1 : 0;
#pragma unroll
    for (int mk = 1; mk < 64; mk <<= 1) c += __shfl_xor(c, mk);
    if ((t & 63) == 0) red2[it & 1][wid] = c;
    __syncthreads();
    int total = red2[it & 1][0] + red2[it & 1][1] + red2[it & 1][2] + red2[it & 1][3];
    if (total >= 512) lo = mid; else hi = mid;
  }
  if (t == 0) {
    unsigned bits = (lo & 0x80000000u) ? (lo & 0x7FFFFFFFu) : ~lo;
    thr[mb] = __uint_as_float(bits);
  }
#pragma unroll
  for (int j = 0; j < 64; ++j) {
    if (code[j] >= lo) {
      int e = j * 256 + t;
      int i = e >> 7, jj = e & 127;
      int slot = atomicAdd(&selcnt[mb * 128 + i], 1);
      if (slot < MAXSEL) selkb[(size_t)(mb * 128 + i) * MAXSEL + slot] = jj;
    }
  }
}

// ---------------- hi branch (online softmax, prefetch, MFMA-norm) + low branch + combine
// 1 wave per (mb, query block). K/V double-buffered in registers; norm via ones-MFMA.
__global__ __launch_bounds__(64) void k_hi(const _Float16* __restrict__ q16,
                                           const _Float16* __restrict__ k16,
                                           const _Float16* __restrict__ v16T,
                                           const int* __restrict__ selcnt,
                                           const int* __restrict__ selkb,
                                           const float* __restrict__ rmax,
                                           const float* __restrict__ thr,
                                           const float* __restrict__ tcv,
                                           const float* __restrict__ vhat,
                                           const float* __restrict__ ll,
                                           const float* __restrict__ am,
                                           float* __restrict__ out) {
  const int bid = blockIdx.x;
  const int mb = bid >> 7, qb = bid & 127;
  const int lane = threadIdx.x;
  const int l15 = lane & 15, quad = lane >> 4;
  const int m2 = mb & 1, b2 = mb >> 4, hh = mb & 15;

  __shared__ _Float16 Ps[32 * 40];

  const _Float16* qbase = q16 + ((size_t)mb * 4096 + qb * 32) * 64;
  half8 aq[2][2];
#pragma unroll
  for (int mt = 0; mt < 2; ++mt)
#pragma unroll
    for (int ks = 0; ks < 2; ++ks)
      aq[mt][ks] = *(const half8*)&qbase[(mt * 16 + l15) * 64 + ks * 32 + quad * 8];

  // ---- low branch (fused old k_lowout): per-lane dim = lane ----
  const float rmaxb = rmax[bid];
  const float th = thr[mb];
  float accL = 0.f, nrmL = 0.f;
#pragma unroll 4
  for (int j = 0; j < 128; ++j) {
    float llv = ll[(size_t)mb * 16384 + (size_t)qb * 128 + j];
    float lrn = llv - rmaxb;
    int di = qb - j;
    if (di <= 1 && di >= -1) lrn += 5000.f;
    float w = (lrn >= th) ? 0.f : __expf(llv - rmaxb) * tcv[m2 * 128 + j];
    accL += w * vhat[((size_t)(mb * 128 + j)) * 64 + lane];
    nrmL += w;
  }

  int nk = selcnt[bid];
  if (nk > MAXSEL) nk = MAXSEL;
  const int* list = selkb + (size_t)bid * MAXSEL;

  const _Float16* kbase  = k16  + (size_t)mb * 4096 * 64;
  const _Float16* vtbase = v16T + (size_t)mb * 64 * 4096;

  float rm[2][4];
  floatx4 o[2][4] = {};
  floatx4 onrm[2] = {};
#pragma unroll
  for (int mt = 0; mt < 2; ++mt)
#pragma unroll
    for (int r = 0; r < 4; ++r) rm[mt][r] = -1e8f;

  half8 ones;
#pragma unroll
  for (int j = 0; j < 8; ++j) ones[j] = (_Float16)1.f;

  half8 kf[2][4], vf[2][4];   // double-buffered K/V fragments
  if (nk > 0) {
    int kb0 = list[0];
    const _Float16* kp = kbase + (size_t)kb0 * 32 * 64;
    kf[0][0] = *(const half8*)&kp[(l15) * 64 + quad * 8];
    kf[0][1] = *(const half8*)&kp[(l15) * 64 + 32 + quad * 8];
    kf[0][2] = *(const half8*)&kp[(16 + l15) * 64 + quad * 8];
    kf[0][3] = *(const half8*)&kp[(16 + l15) * 64 + 32 + quad * 8];
    const _Float16* vp = vtbase + kb0 * 32 + quad * 8;
#pragma unroll
    for (int ntd = 0; ntd < 4; ++ntd)
      vf[0][ntd] = *(const half8*)&vp[(size_t)(ntd * 16 + l15) * 4096];
  }

  for (int t = 0; t < nk; ++t) {
    const int cb = t & 1, nbuf = cb ^ 1;
    const int kb = list[t];
    if (t + 1 < nk) {
      int kbn = list[t + 1];
      const _Float16* kp = kbase + (size_t)kbn * 32 * 64;
      kf[nbuf][0] = *(const half8*)&kp[(l15) * 64 + quad * 8];
      kf[nbuf][1] = *(const half8*)&kp[(l15) * 64 + 32 + quad * 8];
      kf[nbuf][2] = *(const half8*)&kp[(16 + l15) * 64 + quad * 8];
      kf[nbuf][3] = *(const half8*)&kp[(16 + l15) * 64 + 32 + quad * 8];
      const _Float16* vp = vtbase + kbn * 32 + quad * 8;
#pragma unroll
      for (int ntd = 0; ntd < 4; ++ntd)
        vf[nbuf][ntd] = *(const half8*)&vp[(size_t)(ntd * 16 + l15) * 4096];
    }
    floatx4 sf[2][2] = {};
    sf[0][0] = __builtin_amdgcn_mfma_f32_16x16x32_f16(aq[0][0], kf[cb][0], sf[0][0], 0, 0, 0);
    sf[0][0] = __builtin_amdgcn_mfma_f32_16x16x32_f16(aq[0][1], kf[cb][1], sf[0][0], 0, 0, 0);
    sf[0][1] = __builtin_amdgcn_mfma_f32_16x16x32_f16(aq[0][0], kf[cb][2], sf[0][1], 0, 0, 0);
    sf[0][1] = __builtin_amdgcn_mfma_f32_16x16x32_f16(aq[0][1], kf[cb][3], sf[0][1], 0, 0, 0);
    sf[1][0] = __builtin_amdgcn_mfma_f32_16x16x32_f16(aq[1][0], kf[cb][0], sf[1][0], 0, 0, 0);
    sf[1][0] = __builtin_amdgcn_mfma_f32_16x16x32_f16(aq[1][1], kf[cb][1], sf[1][0], 0, 0, 0);
    sf[1][1] = __builtin_amdgcn_mfma_f32_16x16x32_f16(aq[1][0], kf[cb][2], sf[1][1], 0, 0, 0);
    sf[1][1] = __builtin_amdgcn_mfma_f32_16x16x32_f16(aq[1][1], kf[cb][3], sf[1][1], 0, 0, 0);

    float pen0, pen1;
    {
      float mk0 = 1.f + am[m2 * 4096 + kb * 32 + l15] * 1e-4f;
      float mk1 = 1.f + am[m2 * 4096 + kb * 32 + 16 + l15] * 1e-4f;
      pen0 = 10000.f * (1.f - mk0);
      pen1 = 10000.f * (1.f - mk1);
    }
#pragma unroll
    for (int mt = 0; mt < 2; ++mt)
#pragma unroll
      for (int r = 0; r < 4; ++r) {
        float s0 = sf[mt][0][r] * 0.125f;
        float s1 = sf[mt][1][r] * 0.125f;
        float v = fmaxf(s0, s1);
#pragma unroll
        for (int mk = 1; mk < 16; mk <<= 1) v = fmaxf(v, __shfl_xor(v, mk));
        float mnew  = fmaxf(rm[mt][r], v);
        float alpha = __expf(rm[mt][r] - mnew);
        rm[mt][r] = mnew;
        float p0 = __expf(s0 - mnew - pen0);
        float p1 = __expf(s1 - mnew - pen1);
        o[mt][0][r] *= alpha; o[mt][1][r] *= alpha;
        o[mt][2][r] *= alpha; o[mt][3][r] *= alpha;
        onrm[mt][r] *= alpha;
        int row = mt * 16 + quad * 4 + r;
        Ps[row * 40 + l15] = (_Float16)p0;
        Ps[row * 40 + 16 + l15] = (_Float16)p1;
      }
    __syncthreads();
    half8 pa0 = *(const half8*)&Ps[(l15) * 40 + quad * 8];
    half8 pa1 = *(const half8*)&Ps[(16 + l15) * 40 + quad * 8];
#pragma unroll
    for (int ntd = 0; ntd < 4; ++ntd) {
      o[0][ntd] = __builtin_amdgcn_mfma_f32_16x16x32_f16(pa0, vf[cb][ntd], o[0][ntd], 0, 0, 0);
      o[1][ntd] = __builtin_amdgcn_mfma_f32_16x16x32_f16(pa1, vf[cb][ntd], o[1][ntd], 0, 0, 0);
    }
    onrm[0] = __builtin_amdgcn_mfma_f32_16x16x32_f16(pa0, ones, onrm[0], 0, 0, 0);
    onrm[1] = __builtin_amdgcn_mfma_f32_16x16x32_f16(pa1, ones, onrm[1], 0, 0, 0);
    __syncthreads();
  }

  // ---- combine with low branch and write output ----
  float lo_d[4];
#pragma unroll
  for (int ntd = 0; ntd < 4; ++ntd) lo_d[ntd] = __shfl(accL, ntd * 16 + l15);
#pragma unroll
  for (int mt = 0; mt < 2; ++mt) {
#pragma unroll
    for (int r = 0; r < 4; ++r) {
      int q = mt * 16 + quad * 4 + r;
      int qpos = qb * 32 + q;
      float mq = 1.f + am[m2 * 4096 + qpos] * 1e-4f;
      float logc = (rmaxb - rm[mt][r]) * mq;
      float lc = __expf(fminf(logc, 0.f));
      float hc = __expf(-fmaxf(logc, 0.f));
      float den = onrm[mt][r] * hc + nrmL * lc + 1e-6f;
      float sc = mq / den;
#pragma unroll
      for (int ntd = 0; ntd < 4; ++ntd) {
        float val = (o[mt][ntd][r] * hc + lo_d[ntd] * lc) * sc;
        out[((size_t)b2 * 4096 + qpos) * 1024 + hh * 64 + ntd * 16 + l15] = val;
      }
    }
  }
}

// ---------------- host launch ----------------
extern "C" void kernel_launch(void* const* d_in, const int* in_sizes, int n_in,
                              void* d_out, int out_size, void* d_ws, size_t ws_size,
                              hipStream_t stream) {
  const float* hidden = (const float*)d_in[0];
  const float* am     = (const float*)d_in[1];
  const float* wq     = (const float*)d_in[2];
  const float* bq     = (const float*)d_in[3];
  const float* wk     = (const float*)d_in[4];
  const float* bk     = (const float*)d_in[5];
  const float* wv     = (const float*)d_in[6];
  const float* bv     = (const float*)d_in[7];
  float* out = (float*)d_out;

  char* ws = (char*)d_ws;
  size_t off = 0;
  auto alloc = [&](size_t bytes) -> char* {
    char* p = ws + off;
    off += (bytes + 255) & ~(size_t)255;
    return p;
  };
  _Float16* h16    = (_Float16*)alloc((size_t)M8 * H * 2);
  _Float16* w16    = (_Float16*)alloc((size_t)N3 * H * 2);
  _Float16* wlo    = (_Float16*)alloc((size_t)2 * H * H * 2);
  _Float16* q16    = (_Float16*)alloc((size_t)MBH * S * DH * 2);
  _Float16* k16    = (_Float16*)alloc((size_t)MBH * S * DH * 2);
  _Float16* v16T   = (_Float16*)alloc((size_t)MBH * S * DH * 2);
  _Float16* hb_hi  = (_Float16*)alloc((size_t)4 * NB * H * 2);
  _Float16* hb_lo  = (_Float16*)alloc((size_t)4 * NB * H * 2);
  float* tcv       = (float*)alloc((size_t)2 * NB * 4);
  float* sideQK    = (float*)alloc((size_t)4 * NB * 2048 * 4);
  float* ll        = (float*)alloc((size_t)MBH * NB * NB * 4);
  float* rmax      = (float*)alloc((size_t)MBH * NB * 4);
  float* thr       = (float*)alloc((size_t)MBH * 4);
  int*   selcnt    = (int*)alloc((size_t)MBH * NB * 4);
  int*   selkb     = (int*)alloc((size_t)MBH * NB * MAXSEL * 4);
  float* vhat      = (float*)alloc((size_t)MBH * NB * DH * 4);

  hipMemsetAsync(selcnt, 0, (size_t)MBH * NB * 4, stream);

  k_prep<<<dim3(3328), dim3(256), 0, stream>>>(hidden, am, wq, wk, wv,
                                               h16, w16, wlo, hb_hi, hb_lo, tcv);
  k_gemm_qkv<<<dim3(24, 64), dim3(256), 0, stream>>>(h16, w16, bq, bk, bv, am, tcv,
                                                     q16, k16, v16T, vhat);
  k_side<<<dim3(32, 8), dim3(256), 0, stream>>>(hb_hi, hb_lo, w16, wlo, sideQK);
  k_lowlogit<<<dim3(32, 8), dim3(256), 0, stream>>>(sideQK, tcv, bq, bk, ll, rmax);
  k_topk<<<dim3(32), dim3(256), 0, stream>>>(ll, rmax, thr, selcnt, selkb);
  k_hi<<<dim3(4096), dim3(64), 0, stream>>>(q16, k16, v16T, selcnt, selkb, rmax, thr,
                                            tcv, vhat, ll, am, out);
}

// Round 4
// 371.341 us; speedup vs baseline: 5.0555x; 5.0555x over previous
//
#include <hip/hip_runtime.h>
#include <cstdint>
#include <cstddef>

// ---------------- constants ----------------
#define MAXSEL 160
static constexpr int S    = 4096;
static constexpr int H    = 1024;
static constexpr int DH   = 64;
static constexpr int NB   = 128;   // seq blocks (4096/32)
static constexpr int MBH  = 32;    // b*h = 2*16
static constexpr int M8   = 8192;  // 2*4096 rows
static constexpr int N3   = 3072;  // q|k|v features

typedef _Float16 half8 __attribute__((ext_vector_type(8)));
typedef _Float16 half4v __attribute__((ext_vector_type(4)));
typedef float floatx4 __attribute__((ext_vector_type(4)));

__device__ __forceinline__ void load_lds16(const void* g, void* l) {
  __builtin_amdgcn_global_load_lds((const __attribute__((address_space(1))) unsigned int*)g,
                                   (__attribute__((address_space(3))) unsigned int*)l,
                                   16, 0, 0);
}

// ---------------- fused prep: hbar + h16 cast (blocks<256) | weight cast (rest) -------
__global__ __launch_bounds__(256) void k_prep(const float* __restrict__ hidden,
                                              const float* __restrict__ am,
                                              const float* __restrict__ wq,
                                              const float* __restrict__ wk,
                                              const float* __restrict__ wv,
                                              _Float16* __restrict__ h16,
                                              _Float16* __restrict__ w16,
                                              _Float16* __restrict__ wlo,
                                              _Float16* __restrict__ hb_hi,
                                              _Float16* __restrict__ hb_lo,
                                              float* __restrict__ tcv) {
  const int blk_id = blockIdx.x;
  if (blk_id < 256) {
    int b2 = blk_id >> 7, blk = blk_id & 127;
    int c = threadIdx.x * 4;
    float4 s0 = make_float4(0.f, 0.f, 0.f, 0.f);
    float4 s1 = make_float4(0.f, 0.f, 0.f, 0.f);
    for (int i = 0; i < 32; ++i) {
      int pos = blk * 32 + i;
      size_t base = ((size_t)b2 * 4096 + pos) * 1024 + c;
      const float4 x = *(const float4*)&hidden[base];
      half4v h;
      h[0] = (_Float16)x.x; h[1] = (_Float16)x.y;
      h[2] = (_Float16)x.z; h[3] = (_Float16)x.w;
      *(half4v*)&h16[base] = h;
      float m0 = 1.f + am[pos] * 1e-4f;
      float m1 = 1.f + am[4096 + pos] * 1e-4f;
      s0.x += m0 * x.x; s0.y += m0 * x.y; s0.z += m0 * x.z; s0.w += m0 * x.w;
      s1.x += m1 * x.x; s1.y += m1 * x.y; s1.z += m1 * x.z; s1.w += m1 * x.w;
    }
    size_t row0 = (size_t)(b2 * 2 + 0) * 128 + blk;
    size_t row1 = (size_t)(b2 * 2 + 1) * 128 + blk;
    half4v hi, lo;
    hi[0]=(_Float16)s0.x; lo[0]=(_Float16)(s0.x-(float)hi[0]);
    hi[1]=(_Float16)s0.y; lo[1]=(_Float16)(s0.y-(float)hi[1]);
    hi[2]=(_Float16)s0.z; lo[2]=(_Float16)(s0.z-(float)hi[2]);
    hi[3]=(_Float16)s0.w; lo[3]=(_Float16)(s0.w-(float)hi[3]);
    *(half4v*)&hb_hi[row0 * 1024 + c] = hi;
    *(half4v*)&hb_lo[row0 * 1024 + c] = lo;
    hi[0]=(_Float16)s1.x; lo[0]=(_Float16)(s1.x-(float)hi[0]);
    hi[1]=(_Float16)s1.y; lo[1]=(_Float16)(s1.y-(float)hi[1]);
    hi[2]=(_Float16)s1.z; lo[2]=(_Float16)(s1.z-(float)hi[2]);
    hi[3]=(_Float16)s1.w; lo[3]=(_Float16)(s1.w-(float)hi[3]);
    *(half4v*)&hb_hi[row1 * 1024 + c] = hi;
    *(half4v*)&hb_lo[row1 * 1024 + c] = lo;
    if (b2 == 0 && threadIdx.x == 0) {
      float t0 = 0.f, t1 = 0.f;
      for (int i = 0; i < 32; ++i) {
        int pos = blk * 32 + i;
        t0 += 1.f + am[pos] * 1e-4f;
        t1 += 1.f + am[4096 + pos] * 1e-4f;
      }
      tcv[blk] = t0; tcv[128 + blk] = t1;
    }
  } else {
    long j = (long)(blk_id - 256) * 256 + threadIdx.x;   // float4 index into weights
    const long NW4 = (long)H * H / 4;
    int which = (int)(j / NW4);
    long jj = j - (long)which * NW4;
    const float* src = which == 0 ? wq : (which == 1 ? wk : wv);
    float4 x = ((const float4*)src)[jj];
    half4v h;
    h[0] = (_Float16)x.x; h[1] = (_Float16)x.y;
    h[2] = (_Float16)x.z; h[3] = (_Float16)x.w;
    *(half4v*)&w16[j * 4] = h;
    if (which < 2) {
      half4v r;
      r[0] = (_Float16)(x.x - (float)h[0]);
      r[1] = (_Float16)(x.y - (float)h[1]);
      r[2] = (_Float16)(x.z - (float)h[2]);
      r[3] = (_Float16)(x.w - (float)h[3]);
      *(half4v*)&wlo[j * 4] = r;
    }
  }
}

// ---------------- main QKV projection: C(8192x3072) = A(8192x1024) @ W^T, fp16 MFMA ----
// XOR-swizzled LDS (conflict-free, R2-verified). V tiles write v16T (d-major) + vhat
// directly from accumulators; q/k tiles write [s][d] layout.
__global__ __launch_bounds__(256) void k_gemm_qkv(const _Float16* __restrict__ A,
                                                  const _Float16* __restrict__ B,
                                                  const float* __restrict__ bq,
                                                  const float* __restrict__ bk,
                                                  const float* __restrict__ bv,
                                                  const float* __restrict__ am,
                                                  const float* __restrict__ tcv,
                                                  _Float16* __restrict__ q16,
                                                  _Float16* __restrict__ k16,
                                                  _Float16* __restrict__ v16T,
                                                  float* __restrict__ vhat) {
  const int bx = blockIdx.x;           // N tile 0..23
  const int by = blockIdx.y;           // M tile 0..63
  const int tid = threadIdx.x;
  const int lane = tid & 63, wv = tid >> 6;
  const int wm = wv >> 1, wn = wv & 1;
  const int l15 = lane & 15, quad = lane >> 4;

  __shared__ _Float16 As[128 * 64];
  __shared__ _Float16 Bs[128 * 64];

  floatx4 acc[4][4] = {};

  const _Float16* Ag = A + (size_t)(by * 128) * 1024;
  const _Float16* Bg = B + (size_t)(bx * 128) * 1024;
  const int srow_l = lane >> 3;                              // 0..7
  const int scol   = (((lane & 7) ^ (srow_l & 7)) * 8);      // swizzled source chunk
  const int swz    = l15 & 7;

  for (int k0 = 0; k0 < 1024; k0 += 64) {
    __syncthreads();
#pragma unroll
    for (int i = 0; i < 4; ++i) {
      int rb = i * 32 + wv * 8;
      load_lds16(Ag + (size_t)(rb + srow_l) * 1024 + k0 + scol, &As[rb * 64]);
      load_lds16(Bg + (size_t)(rb + srow_l) * 1024 + k0 + scol, &Bs[rb * 64]);
    }
    __syncthreads();
#pragma unroll
    for (int ks = 0; ks < 2; ++ks) {
      const int kc = ks * 4;
      half8 a[4], b[4];
#pragma unroll
      for (int mt = 0; mt < 4; ++mt)
        a[mt] = *(const half8*)&As[(wm * 64 + mt * 16 + l15) * 64 + (((kc + quad) ^ swz) << 3)];
#pragma unroll
      for (int nt = 0; nt < 4; ++nt)
        b[nt] = *(const half8*)&Bs[(wn * 64 + nt * 16 + l15) * 64 + (((kc + quad) ^ swz) << 3)];
#pragma unroll
      for (int mt = 0; mt < 4; ++mt)
#pragma unroll
        for (int nt = 0; nt < 4; ++nt)
          acc[mt][nt] = __builtin_amdgcn_mfma_f32_16x16x32_f16(a[mt], b[nt], acc[mt][nt], 0, 0, 0);
    }
  }

  const int which = (bx * 128) >> 10;  // uniform per CTA: 0=q 1=k 2=v
  if (which == 2) {
    // ---- V epilogue: v16T (d-major) + vhat block means ----
    const int mrow0 = by * 128 + wm * 64;      // 64-aligned; never straddles 4096
    const int b2 = mrow0 >> 12;
    const int sbase = mrow0 & 4095;
    const int blkA = sbase >> 5;               // even block
    const int hh = ((bx * 128 + wn * 64) >> 6) & 15;
    const int m2 = hh & 1;
    const int mb = b2 * 16 + hh;
#pragma unroll
    for (int nt = 0; nt < 4; ++nt) {
      int oo = (bx * 128 + wn * 64 + nt * 16 + l15) & 1023;
      int dd = oo & 63;                        // = nt*16 + l15
      float bsv = bv[oo];
      float sA = 0.f, sB = 0.f;
#pragma unroll
      for (int mt = 0; mt < 4; ++mt) {
        half4v vv;
#pragma unroll
        for (int r = 0; r < 4; ++r) {
          int s = sbase + mt * 16 + quad * 4 + r;
          float mv = 1.f + am[m2 * 4096 + s] * 1e-4f;
          float v = (acc[mt][nt][r] + bsv) * mv;
          vv[r] = (_Float16)v;
          if (mt < 2) sA += v; else sB += v;
        }
        int s0 = sbase + mt * 16 + quad * 4;
        *(half4v*)&v16T[((size_t)(mb * 64 + dd)) * 4096 + s0] = vv;
      }
      sA += __shfl_xor(sA, 16); sA += __shfl_xor(sA, 32);
      sB += __shfl_xor(sB, 16); sB += __shfl_xor(sB, 32);
      if (quad == 0)
        vhat[((size_t)(mb * 128 + blkA)) * 64 + dd]     = sA / (tcv[m2 * 128 + blkA] + 1e-6f);
      else if (quad == 1)
        vhat[((size_t)(mb * 128 + blkA + 1)) * 64 + dd] = sB / (tcv[m2 * 128 + blkA + 1] + 1e-6f);
    }
  } else {
    const float* bias = which == 0 ? bq : bk;
    _Float16* dst = which == 0 ? q16 : k16;
#pragma unroll
    for (int nt = 0; nt < 4; ++nt) {
      int o  = bx * 128 + wn * 64 + nt * 16 + l15;
      int oo = o & 1023;
      int hh = oo >> 6, dd = oo & 63;
      int m2 = hh & 1;
      float bsv = bias[oo];
#pragma unroll
      for (int mt = 0; mt < 4; ++mt) {
#pragma unroll
        for (int r = 0; r < 4; ++r) {
          int srow = by * 128 + wm * 64 + mt * 16 + quad * 4 + r;
          int b2 = srow >> 12, s = srow & 4095;
          float mv = 1.f + am[m2 * 4096 + s] * 1e-4f;
          float v = (acc[mt][nt][r] + bsv) * mv;
          int mb = b2 * 16 + hh;
          dst[((size_t)mb * 4096 + s) * 64 + dd] = (_Float16)v;
        }
      }
    }
  }
}

// ---------------- fp16x3 GEMM (pre-split inputs): sideQK(512x2048) = hbar @ [wq;wk]^T --
__global__ __launch_bounds__(256) void k_side(const _Float16* __restrict__ Ahi,
                                              const _Float16* __restrict__ Alo,
                                              const _Float16* __restrict__ Bhi,
                                              const _Float16* __restrict__ Blo,
                                              float* __restrict__ sideQK) {
  const int bx = blockIdx.x;   // 0..31 (N/64)
  const int by = blockIdx.y;   // 0..7  (M/64)
  const int tid = threadIdx.x;
  const int lane = tid & 63, wv = tid >> 6;
  const int wm = wv >> 1, wn = wv & 1;
  const int l15 = lane & 15, quad = lane >> 4;

  __shared__ _Float16 sAhi[64*64], sAlo[64*64], sBhi[64*64], sBlo[64*64];
  floatx4 acc[2][2] = {};

  const int srow = lane >> 3;
  const int scol = (((lane & 7) ^ (srow & 7)) * 8);
  const int swz  = l15 & 7;
  const _Float16* src;
  _Float16* dst;
  if      (wv == 0) { src = Ahi + (size_t)(by * 64) * 1024; dst = sAhi; }
  else if (wv == 1) { src = Alo + (size_t)(by * 64) * 1024; dst = sAlo; }
  else if (wv == 2) { src = Bhi + (size_t)(bx * 64) * 1024; dst = sBhi; }
  else              { src = Blo + (size_t)(bx * 64) * 1024; dst = sBlo; }

  for (int k0 = 0; k0 < 1024; k0 += 64) {
    __syncthreads();
#pragma unroll
    for (int i = 0; i < 8; ++i)
      load_lds16(src + (size_t)(i * 8 + srow) * 1024 + k0 + scol, dst + i * 512);
    __syncthreads();
#pragma unroll
    for (int ks = 0; ks < 2; ++ks) {
      const int kc = ks * 4;
      half8 ah[2], al[2], bh[2], bl[2];
#pragma unroll
      for (int mt = 0; mt < 2; ++mt) {
        int off = (wm * 32 + mt * 16 + l15) * 64 + (((kc + quad) ^ swz) << 3);
        ah[mt] = *(const half8*)&sAhi[off];
        al[mt] = *(const half8*)&sAlo[off];
      }
#pragma unroll
      for (int nt = 0; nt < 2; ++nt) {
        int off = (wn * 32 + nt * 16 + l15) * 64 + (((kc + quad) ^ swz) << 3);
        bh[nt] = *(const half8*)&sBhi[off];
        bl[nt] = *(const half8*)&sBlo[off];
      }
#pragma unroll
      for (int mt = 0; mt < 2; ++mt)
#pragma unroll
        for (int nt = 0; nt < 2; ++nt) {
          acc[mt][nt] = __builtin_amdgcn_mfma_f32_16x16x32_f16(ah[mt], bh[nt], acc[mt][nt], 0, 0, 0);
          acc[mt][nt] = __builtin_amdgcn_mfma_f32_16x16x32_f16(ah[mt], bl[nt], acc[mt][nt], 0, 0, 0);
          acc[mt][nt] = __builtin_amdgcn_mfma_f32_16x16x32_f16(al[mt], bh[nt], acc[mt][nt], 0, 0, 0);
        }
    }
  }
#pragma unroll
  for (int mt = 0; mt < 2; ++mt)
#pragma unroll
    for (int nt = 0; nt < 2; ++nt)
#pragma unroll
      for (int rr = 0; rr < 4; ++rr) {
        int row = by * 64 + wm * 32 + mt * 16 + quad * 4 + rr;
        int col = bx * 64 + wn * 32 + nt * 16 + l15;
        sideQK[(size_t)row * 2048 + col] = acc[mt][nt][rr];
      }
}

// ---------------- low-resolution logits + row max (conflict-free, rotated d) ----------
__global__ __launch_bounds__(256) void k_lowlogit(const float* __restrict__ sideQK,
                                                  const float* __restrict__ tcv,
                                                  const float* __restrict__ bq,
                                                  const float* __restrict__ bk,
                                                  float* __restrict__ ll,
                                                  float* __restrict__ rmaxout) {
  const int mb = blockIdx.x;
  const int ib = blockIdx.y;       // 0..7 : rows ib*16..+16
  const int b2 = mb >> 4, m2 = mb & 1, hh = mb & 15;
  const int combo = b2 * 2 + m2;
  const int tid = threadIdx.x;
  __shared__ float Kh[128 * 64];
  __shared__ float Qh[16 * 64];
  __shared__ float tcL[128];

  if (tid < 128) tcL[tid] = tcv[m2 * 128 + tid];
  __syncthreads();
#pragma unroll
  for (int i = 0; i < 8; ++i) {
    int ci = tid + i * 256;
    int row = ci >> 4, c4 = (ci & 15) * 4;
    float tck = tcL[row];
    float den = 1.f / (tck + 1e-6f);
    float4 x  = *(const float4*)&sideQK[((size_t)combo * 128 + row) * 2048 + 1024 + hh * 64 + c4];
    float4 bb = *(const float4*)&bk[hh * 64 + c4];
    float4 o;
    o.x = (x.x + bb.x * tck) * den; o.y = (x.y + bb.y * tck) * den;
    o.z = (x.z + bb.z * tck) * den; o.w = (x.w + bb.w * tck) * den;
    *(float4*)&Kh[row * 64 + c4] = o;
  }
  {
    int row = tid >> 4, c4 = (tid & 15) * 4;
    int gi = ib * 16 + row;
    float tcq = tcL[gi];
    float den = 1.f / (tcq + 1e-6f);
    float4 x  = *(const float4*)&sideQK[((size_t)combo * 128 + gi) * 2048 + hh * 64 + c4];
    float4 bb = *(const float4*)&bq[hh * 64 + c4];
    float4 o;
    o.x = (x.x + bb.x * tcq) * den; o.y = (x.y + bb.y * tcq) * den;
    o.z = (x.z + bb.z * tcq) * den; o.w = (x.w + bb.w * tcq) * den;
    *(float4*)&Qh[row * 64 + c4] = o;
  }
  __syncthreads();

  const int il = tid >> 4, jg = tid & 15;
  const int i = ib * 16 + il;
  float tcq = tcL[i];
  float dots[8] = {};
#pragma unroll
  for (int dd = 0; dd < 16; ++dd) {
    int d4 = ((dd + tid) & 15) * 4;       // lane-rotated: conflict-free LDS columns
    float4 qv = *(const float4*)&Qh[il * 64 + d4];
#pragma unroll
    for (int jj = 0; jj < 8; ++jj) {
      float4 kv = *(const float4*)&Kh[(jg * 8 + jj) * 64 + d4];
      dots[jj] += qv.x * kv.x + qv.y * kv.y + qv.z * kv.z + qv.w * kv.w;
    }
  }
  float tmax = -1e30f;
#pragma unroll
  for (int jj = 0; jj < 8; ++jj) {
    int j = jg * 8 + jj;
    float raw = dots[jj] * 0.125f;
    tmax = fmaxf(tmax, raw);
    float pen = (tcq * tcL[j] < 0.5f) ? 10000.f : 0.f;
    ll[(size_t)mb * 16384 + (size_t)i * 128 + j] = raw - pen;
  }
#pragma unroll
  for (int mk = 1; mk < 16; mk <<= 1) tmax = fmaxf(tmax, __shfl_xor(tmax, mk));
  if (jg == 0) rmaxout[mb * 128 + i] = tmax;
}

// ---------------- exact top-512 threshold + selected-block buckets --------------------
__global__ __launch_bounds__(256) void k_topk(const float* __restrict__ ll,
                                              const float* __restrict__ rmax,
                                              float* __restrict__ thr,
                                              int* __restrict__ selcnt,
                                              int* __restrict__ selkb) {
  const int mb = blockIdx.x;
  const int t = threadIdx.x;
  const int wid = t >> 6;
  __shared__ int red2[2][4];

  unsigned code[64];
#pragma unroll
  for (int j = 0; j < 64; ++j) {
    int e = j * 256 + t;
    int i = e >> 7, jj = e & 127;
    float lrn = ll[(size_t)mb * 16384 + e] - rmax[mb * 128 + i];
    int di = i - jj;
    if (di <= 1 && di >= -1) lrn += 5000.f;
    unsigned b = __float_as_uint(lrn);
    code[j] = (b & 0x80000000u) ? ~b : (b | 0x80000000u);
  }

  unsigned lo = 0u, hi = 0xFFFFFFFFu;
  for (int it = 0; it < 32; ++it) {
    unsigned mid = lo + ((hi - lo) >> 1);
    int c = 0;
#pragma unroll
    for (int j = 0; j < 64; ++j) c += (code[j] >= mid) ? 1 : 0;
#pragma unroll
    for (int mk = 1; mk < 64; mk <<= 1) c += __shfl_xor(c, mk);
    if ((t & 63) == 0) red2[it & 1][wid] = c;
    __syncthreads();
    int total = red2[it & 1][0] + red2[it & 1][1] + red2[it & 1][2] + red2[it & 1][3];
    if (total >= 512) lo = mid; else hi = mid;
  }
  if (t == 0) {
    unsigned bits = (lo & 0x80000000u) ? (lo & 0x7FFFFFFFu) : ~lo;
    thr[mb] = __uint_as_float(bits);
  }
#pragma unroll
  for (int j = 0; j < 64; ++j) {
    if (code[j] >= lo) {
      int e = j * 256 + t;
      int i = e >> 7, jj = e & 127;
      int slot = atomicAdd(&selcnt[mb * 128 + i], 1);
      if (slot < MAXSEL) selkb[(size_t)(mb * 128 + i) * MAXSEL + slot] = jj;
    }
  }
}

// ---------------- hi branch (online softmax, MFMA-norm) + low branch + combine --------
// 1 wave per (mb, query block). All fragment temporaries use compile-time indices ONLY
// (runtime-indexed register arrays lower to scratch on AMDGPU — R3's 20x regression).
__global__ __launch_bounds__(64) void k_hi(const _Float16* __restrict__ q16,
                                           const _Float16* __restrict__ k16,
                                           const _Float16* __restrict__ v16T,
                                           const int* __restrict__ selcnt,
                                           const int* __restrict__ selkb,
                                           const float* __restrict__ rmax,
                                           const float* __restrict__ thr,
                                           const float* __restrict__ tcv,
                                           const float* __restrict__ vhat,
                                           const float* __restrict__ ll,
                                           const float* __restrict__ am,
                                           float* __restrict__ out) {
  const int bid = blockIdx.x;
  const int mb = bid >> 7, qb = bid & 127;
  const int lane = threadIdx.x;
  const int l15 = lane & 15, quad = lane >> 4;
  const int m2 = mb & 1, b2 = mb >> 4, hh = mb & 15;

  __shared__ _Float16 Ps[32 * 40];

  const _Float16* qbase = q16 + ((size_t)mb * 4096 + qb * 32) * 64;
  half8 aq[2][2];
#pragma unroll
  for (int mt = 0; mt < 2; ++mt)
#pragma unroll
    for (int ks = 0; ks < 2; ++ks)
      aq[mt][ks] = *(const half8*)&qbase[(mt * 16 + l15) * 64 + ks * 32 + quad * 8];

  // ---- low branch (block-level; same for all 32 q rows). lane = dim ----
  const float rmaxb = rmax[bid];
  const float th = thr[mb];
  float accL = 0.f, nrmL = 0.f;
#pragma unroll 4
  for (int j = 0; j < 128; ++j) {
    float llv = ll[(size_t)mb * 16384 + (size_t)qb * 128 + j];
    float lrn = llv - rmaxb;
    int di = qb - j;
    if (di <= 1 && di >= -1) lrn += 5000.f;
    float w = (lrn >= th) ? 0.f : __expf(llv - rmaxb) * tcv[m2 * 128 + j];
    accL += w * vhat[((size_t)(mb * 128 + j)) * 64 + lane];
    nrmL += w;
  }

  int nk = selcnt[bid];
  if (nk > MAXSEL) nk = MAXSEL;
  const int* list = selkb + (size_t)bid * MAXSEL;

  const _Float16* kbase  = k16  + (size_t)mb * 4096 * 64;
  const _Float16* vtbase = v16T + (size_t)mb * 64 * 4096;

  float rm[2][4];
  floatx4 o[2][4] = {};
  floatx4 onrm[2] = {};
#pragma unroll
  for (int mt = 0; mt < 2; ++mt)
#pragma unroll
    for (int r = 0; r < 4; ++r) rm[mt][r] = -1e8f;

  half8 ones;
#pragma unroll
  for (int j = 0; j < 8; ++j) ones[j] = (_Float16)1.f;

  for (int t = 0; t < nk; ++t) {
    const int kb = list[t];
    const _Float16* kp = kbase + (size_t)kb * 32 * 64;
    half8 b0[2], b1[2];
#pragma unroll
    for (int ks = 0; ks < 2; ++ks) {
      b0[ks] = *(const half8*)&kp[(l15) * 64 + ks * 32 + quad * 8];
      b1[ks] = *(const half8*)&kp[(16 + l15) * 64 + ks * 32 + quad * 8];
    }
    // V fragments issued early: latency overlapped with QK-MFMA + softmax below
    const _Float16* vp = vtbase + kb * 32 + quad * 8;
    half8 vb0 = *(const half8*)&vp[(size_t)(l15) * 4096];
    half8 vb1 = *(const half8*)&vp[(size_t)(16 + l15) * 4096];
    half8 vb2 = *(const half8*)&vp[(size_t)(32 + l15) * 4096];
    half8 vb3 = *(const half8*)&vp[(size_t)(48 + l15) * 4096];

    floatx4 sf[2][2] = {};
    sf[0][0] = __builtin_amdgcn_mfma_f32_16x16x32_f16(aq[0][0], b0[0], sf[0][0], 0, 0, 0);
    sf[0][0] = __builtin_amdgcn_mfma_f32_16x16x32_f16(aq[0][1], b0[1], sf[0][0], 0, 0, 0);
    sf[0][1] = __builtin_amdgcn_mfma_f32_16x16x32_f16(aq[0][0], b1[0], sf[0][1], 0, 0, 0);
    sf[0][1] = __builtin_amdgcn_mfma_f32_16x16x32_f16(aq[0][1], b1[1], sf[0][1], 0, 0, 0);
    sf[1][0] = __builtin_amdgcn_mfma_f32_16x16x32_f16(aq[1][0], b0[0], sf[1][0], 0, 0, 0);
    sf[1][0] = __builtin_amdgcn_mfma_f32_16x16x32_f16(aq[1][1], b0[1], sf[1][0], 0, 0, 0);
    sf[1][1] = __builtin_amdgcn_mfma_f32_16x16x32_f16(aq[1][0], b1[0], sf[1][1], 0, 0, 0);
    sf[1][1] = __builtin_amdgcn_mfma_f32_16x16x32_f16(aq[1][1], b1[1], sf[1][1], 0, 0, 0);

    float pen0, pen1;
    {
      float mk0 = 1.f + am[m2 * 4096 + kb * 32 + l15] * 1e-4f;
      float mk1 = 1.f + am[m2 * 4096 + kb * 32 + 16 + l15] * 1e-4f;
      pen0 = 10000.f * (1.f - mk0);
      pen1 = 10000.f * (1.f - mk1);
    }
#pragma unroll
    for (int mt = 0; mt < 2; ++mt)
#pragma unroll
      for (int r = 0; r < 4; ++r) {
        float s0 = sf[mt][0][r] * 0.125f;
        float s1 = sf[mt][1][r] * 0.125f;
        float v = fmaxf(s0, s1);
#pragma unroll
        for (int mk = 1; mk < 16; mk <<= 1) v = fmaxf(v, __shfl_xor(v, mk));
        float mnew  = fmaxf(rm[mt][r], v);
        float alpha = __expf(rm[mt][r] - mnew);
        rm[mt][r] = mnew;
        float p0 = __expf(s0 - mnew - pen0);
        float p1 = __expf(s1 - mnew - pen1);
        o[mt][0][r] *= alpha; o[mt][1][r] *= alpha;
        o[mt][2][r] *= alpha; o[mt][3][r] *= alpha;
        onrm[mt][r] *= alpha;
        int row = mt * 16 + quad * 4 + r;
        Ps[row * 40 + l15] = (_Float16)p0;
        Ps[row * 40 + 16 + l15] = (_Float16)p1;
      }
    __syncthreads();
    half8 pa0 = *(const half8*)&Ps[(l15) * 40 + quad * 8];
    half8 pa1 = *(const half8*)&Ps[(16 + l15) * 40 + quad * 8];
    o[0][0] = __builtin_amdgcn_mfma_f32_16x16x32_f16(pa0, vb0, o[0][0], 0, 0, 0);
    o[0][1] = __builtin_amdgcn_mfma_f32_16x16x32_f16(pa0, vb1, o[0][1], 0, 0, 0);
    o[0][2] = __builtin_amdgcn_mfma_f32_16x16x32_f16(pa0, vb2, o[0][2], 0, 0, 0);
    o[0][3] = __builtin_amdgcn_mfma_f32_16x16x32_f16(pa0, vb3, o[0][3], 0, 0, 0);
    o[1][0] = __builtin_amdgcn_mfma_f32_16x16x32_f16(pa1, vb0, o[1][0], 0, 0, 0);
    o[1][1] = __builtin_amdgcn_mfma_f32_16x16x32_f16(pa1, vb1, o[1][1], 0, 0, 0);
    o[1][2] = __builtin_amdgcn_mfma_f32_16x16x32_f16(pa1, vb2, o[1][2], 0, 0, 0);
    o[1][3] = __builtin_amdgcn_mfma_f32_16x16x32_f16(pa1, vb3, o[1][3], 0, 0, 0);
    onrm[0] = __builtin_amdgcn_mfma_f32_16x16x32_f16(pa0, ones, onrm[0], 0, 0, 0);
    onrm[1] = __builtin_amdgcn_mfma_f32_16x16x32_f16(pa1, ones, onrm[1], 0, 0, 0);
    __syncthreads();
  }

  // ---- combine with low branch and write output ----
  float lo_d[4];
#pragma unroll
  for (int ntd = 0; ntd < 4; ++ntd) lo_d[ntd] = __shfl(accL, ntd * 16 + l15);
#pragma unroll
  for (int mt = 0; mt < 2; ++mt) {
#pragma unroll
    for (int r = 0; r < 4; ++r) {
      int q = mt * 16 + quad * 4 + r;
      int qpos = qb * 32 + q;
      float mq = 1.f + am[m2 * 4096 + qpos] * 1e-4f;
      float logc = (rmaxb - rm[mt][r]) * mq;
      float lc = __expf(fminf(logc, 0.f));
      float hc = __expf(-fmaxf(logc, 0.f));
      float den = onrm[mt][r] * hc + nrmL * lc + 1e-6f;
      float sc = mq / den;
#pragma unroll
      for (int ntd = 0; ntd < 4; ++ntd) {
        float val = (o[mt][ntd][r] * hc + lo_d[ntd] * lc) * sc;
        out[((size_t)b2 * 4096 + qpos) * 1024 + hh * 64 + ntd * 16 + l15] = val;
      }
    }
  }
}

// ---------------- host launch ----------------
extern "C" void kernel_launch(void* const* d_in, const int* in_sizes, int n_in,
                              void* d_out, int out_size, void* d_ws, size_t ws_size,
                              hipStream_t stream) {
  const float* hidden = (const float*)d_in[0];
  const float* am     = (const float*)d_in[1];
  const float* wq     = (const float*)d_in[2];
  const float* bq     = (const float*)d_in[3];
  const float* wk     = (const float*)d_in[4];
  const float* bk     = (const float*)d_in[5];
  const float* wv     = (const float*)d_in[6];
  const float* bv     = (const float*)d_in[7];
  float* out = (float*)d_out;

  char* ws = (char*)d_ws;
  size_t off = 0;
  auto alloc = [&](size_t bytes) -> char* {
    char* p = ws + off;
    off += (bytes + 255) & ~(size_t)255;
    return p;
  };
  _Float16* h16    = (_Float16*)alloc((size_t)M8 * H * 2);
  _Float16* w16    = (_Float16*)alloc((size_t)N3 * H * 2);
  _Float16* wlo    = (_Float16*)alloc((size_t)2 * H * H * 2);
  _Float16* q16    = (_Float16*)alloc((size_t)MBH * S * DH * 2);
  _Float16* k16    = (_Float16*)alloc((size_t)MBH * S * DH * 2);
  _Float16* v16T   = (_Float16*)alloc((size_t)MBH * S * DH * 2);
  _Float16* hb_hi  = (_Float16*)alloc((size_t)4 * NB * H * 2);
  _Float16* hb_lo  = (_Float16*)alloc((size_t)4 * NB * H * 2);
  float* tcv       = (float*)alloc((size_t)2 * NB * 4);
  float* sideQK    = (float*)alloc((size_t)4 * NB * 2048 * 4);
  float* ll        = (float*)alloc((size_t)MBH * NB * NB * 4);
  float* rmax      = (float*)alloc((size_t)MBH * NB * 4);
  float* thr       = (float*)alloc((size_t)MBH * 4);
  int*   selcnt    = (int*)alloc((size_t)MBH * NB * 4);
  int*   selkb     = (int*)alloc((size_t)MBH * NB * MAXSEL * 4);
  float* vhat      = (float*)alloc((size_t)MBH * NB * DH * 4);

  hipMemsetAsync(selcnt, 0, (size_t)MBH * NB * 4, stream);

  k_prep<<<dim3(3328), dim3(256), 0, stream>>>(hidden, am, wq, wk, wv,
                                               h16, w16, wlo, hb_hi, hb_lo, tcv);
  k_gemm_qkv<<<dim3(24, 64), dim3(256), 0, stream>>>(h16, w16, bq, bk, bv, am, tcv,
                                                     q16, k16, v16T, vhat);
  k_side<<<dim3(32, 8), dim3(256), 0, stream>>>(hb_hi, hb_lo, w16, wlo, sideQK);
  k_lowlogit<<<dim3(32, 8), dim3(256), 0, stream>>>(sideQK, tcv, bq, bk, ll, rmax);
  k_topk<<<dim3(32), dim3(256), 0, stream>>>(ll, rmax, thr, selcnt, selkb);
  k_hi<<<dim3(4096), dim3(64), 0, stream>>>(q16, k16, v16T, selcnt, selkb, rmax, thr,
                                            tcv, vhat, ll, am, out);
}

// Round 5
// 319.036 us; speedup vs baseline: 5.8844x; 1.1639x over previous
//
#include <hip/hip_runtime.h>
#include <cstdint>
#include <cstddef>

// ---------------- constants ----------------
#define MAXSEL 160
static constexpr int S    = 4096;
static constexpr int H    = 1024;
static constexpr int DH   = 64;
static constexpr int NB   = 128;   // seq blocks (4096/32)
static constexpr int MBH  = 32;    // b*h = 2*16
static constexpr int M8   = 8192;  // 2*4096 rows
static constexpr int N3   = 3072;  // q|k|v features

typedef _Float16 half8 __attribute__((ext_vector_type(8)));
typedef _Float16 half4v __attribute__((ext_vector_type(4)));
typedef float floatx4 __attribute__((ext_vector_type(4)));

__device__ __forceinline__ void load_lds16(const void* g, void* l) {
  __builtin_amdgcn_global_load_lds((const __attribute__((address_space(1))) unsigned int*)g,
                                   (__attribute__((address_space(3))) unsigned int*)l,
                                   16, 0, 0);
}

// ---------------- fused prep: hbar + h16 cast | weight cast | selcnt zero -------------
__global__ __launch_bounds__(256) void k_prep(const float* __restrict__ hidden,
                                              const float* __restrict__ am,
                                              const float* __restrict__ wq,
                                              const float* __restrict__ wk,
                                              const float* __restrict__ wv,
                                              _Float16* __restrict__ h16,
                                              _Float16* __restrict__ w16,
                                              _Float16* __restrict__ wlo,
                                              _Float16* __restrict__ hb_hi,
                                              _Float16* __restrict__ hb_lo,
                                              float* __restrict__ tcv,
                                              int* __restrict__ selcnt) {
  const int blk_id = blockIdx.x;
  if (blk_id < 256) {
    if (blk_id == 0) {
      for (int i = threadIdx.x; i < MBH * NB; i += 256) selcnt[i] = 0;
    }
    int b2 = blk_id >> 7, blk = blk_id & 127;
    int c = threadIdx.x * 4;
    float4 s0 = make_float4(0.f, 0.f, 0.f, 0.f);
    float4 s1 = make_float4(0.f, 0.f, 0.f, 0.f);
    for (int i = 0; i < 32; ++i) {
      int pos = blk * 32 + i;
      size_t base = ((size_t)b2 * 4096 + pos) * 1024 + c;
      const float4 x = *(const float4*)&hidden[base];
      half4v h;
      h[0] = (_Float16)x.x; h[1] = (_Float16)x.y;
      h[2] = (_Float16)x.z; h[3] = (_Float16)x.w;
      *(half4v*)&h16[base] = h;
      float m0 = 1.f + am[pos] * 1e-4f;
      float m1 = 1.f + am[4096 + pos] * 1e-4f;
      s0.x += m0 * x.x; s0.y += m0 * x.y; s0.z += m0 * x.z; s0.w += m0 * x.w;
      s1.x += m1 * x.x; s1.y += m1 * x.y; s1.z += m1 * x.z; s1.w += m1 * x.w;
    }
    size_t row0 = (size_t)(b2 * 2 + 0) * 128 + blk;
    size_t row1 = (size_t)(b2 * 2 + 1) * 128 + blk;
    half4v hi, lo;
    hi[0]=(_Float16)s0.x; lo[0]=(_Float16)(s0.x-(float)hi[0]);
    hi[1]=(_Float16)s0.y; lo[1]=(_Float16)(s0.y-(float)hi[1]);
    hi[2]=(_Float16)s0.z; lo[2]=(_Float16)(s0.z-(float)hi[2]);
    hi[3]=(_Float16)s0.w; lo[3]=(_Float16)(s0.w-(float)hi[3]);
    *(half4v*)&hb_hi[row0 * 1024 + c] = hi;
    *(half4v*)&hb_lo[row0 * 1024 + c] = lo;
    hi[0]=(_Float16)s1.x; lo[0]=(_Float16)(s1.x-(float)hi[0]);
    hi[1]=(_Float16)s1.y; lo[1]=(_Float16)(s1.y-(float)hi[1]);
    hi[2]=(_Float16)s1.z; lo[2]=(_Float16)(s1.z-(float)hi[2]);
    hi[3]=(_Float16)s1.w; lo[3]=(_Float16)(s1.w-(float)hi[3]);
    *(half4v*)&hb_hi[row1 * 1024 + c] = hi;
    *(half4v*)&hb_lo[row1 * 1024 + c] = lo;
    if (b2 == 0 && threadIdx.x == 0) {
      float t0 = 0.f, t1 = 0.f;
      for (int i = 0; i < 32; ++i) {
        int pos = blk * 32 + i;
        t0 += 1.f + am[pos] * 1e-4f;
        t1 += 1.f + am[4096 + pos] * 1e-4f;
      }
      tcv[blk] = t0; tcv[128 + blk] = t1;
    }
  } else {
    long j = (long)(blk_id - 256) * 256 + threadIdx.x;   // float4 index into weights
    const long NW4 = (long)H * H / 4;
    int which = (int)(j / NW4);
    long jj = j - (long)which * NW4;
    const float* src = which == 0 ? wq : (which == 1 ? wk : wv);
    float4 x = ((const float4*)src)[jj];
    half4v h;
    h[0] = (_Float16)x.x; h[1] = (_Float16)x.y;
    h[2] = (_Float16)x.z; h[3] = (_Float16)x.w;
    *(half4v*)&w16[j * 4] = h;
    if (which < 2) {
      half4v r;
      r[0] = (_Float16)(x.x - (float)h[0]);
      r[1] = (_Float16)(x.y - (float)h[1]);
      r[2] = (_Float16)(x.z - (float)h[2]);
      r[3] = (_Float16)(x.w - (float)h[3]);
      *(half4v*)&wlo[j * 4] = r;
    }
  }
}

// ---------------- main QKV projection (R2 form, VGPR 112): C = A @ W^T, fp16 MFMA -----
// XOR-swizzled LDS (conflict-free). Plain q/k/v epilogue — V transpose done elsewhere
// (fusing it here costs 36 VGPR -> 1 wave/SIMD -> 1.7x GEMM slowdown; R4 post-mortem).
__global__ __launch_bounds__(256) void k_gemm_qkv(const _Float16* __restrict__ A,
                                                  const _Float16* __restrict__ B,
                                                  const float* __restrict__ bq,
                                                  const float* __restrict__ bk,
                                                  const float* __restrict__ bv,
                                                  const float* __restrict__ am,
                                                  _Float16* __restrict__ q16,
                                                  _Float16* __restrict__ k16,
                                                  _Float16* __restrict__ v16) {
  const int bx = blockIdx.x;           // N tile 0..23
  const int by = blockIdx.y;           // M tile 0..63
  const int tid = threadIdx.x;
  const int lane = tid & 63, wv = tid >> 6;
  const int wm = wv >> 1, wn = wv & 1;
  const int l15 = lane & 15, quad = lane >> 4;

  __shared__ _Float16 As[128 * 64];
  __shared__ _Float16 Bs[128 * 64];

  floatx4 acc[4][4] = {};

  const _Float16* Ag = A + (size_t)(by * 128) * 1024;
  const _Float16* Bg = B + (size_t)(bx * 128) * 1024;
  const int srow_l = lane >> 3;                              // 0..7
  const int scol   = (((lane & 7) ^ (srow_l & 7)) * 8);      // swizzled source chunk
  const int swz    = l15 & 7;

  for (int k0 = 0; k0 < 1024; k0 += 64) {
    __syncthreads();
#pragma unroll
    for (int i = 0; i < 4; ++i) {
      int rb = i * 32 + wv * 8;
      load_lds16(Ag + (size_t)(rb + srow_l) * 1024 + k0 + scol, &As[rb * 64]);
      load_lds16(Bg + (size_t)(rb + srow_l) * 1024 + k0 + scol, &Bs[rb * 64]);
    }
    __syncthreads();
#pragma unroll
    for (int ks = 0; ks < 2; ++ks) {
      const int kc = ks * 4;
      half8 a[4], b[4];
#pragma unroll
      for (int mt = 0; mt < 4; ++mt)
        a[mt] = *(const half8*)&As[(wm * 64 + mt * 16 + l15) * 64 + (((kc + quad) ^ swz) << 3)];
#pragma unroll
      for (int nt = 0; nt < 4; ++nt)
        b[nt] = *(const half8*)&Bs[(wn * 64 + nt * 16 + l15) * 64 + (((kc + quad) ^ swz) << 3)];
#pragma unroll
      for (int mt = 0; mt < 4; ++mt)
#pragma unroll
        for (int nt = 0; nt < 4; ++nt)
          acc[mt][nt] = __builtin_amdgcn_mfma_f32_16x16x32_f16(a[mt], b[nt], acc[mt][nt], 0, 0, 0);
    }
  }

  // epilogue: scatter to q16/k16/v16 in (mb, s, dd) layout, + bias, * mask
  const int which = (bx * 128) >> 10;  // uniform per CTA
  const float* bias = which == 0 ? bq : (which == 1 ? bk : bv);
  _Float16* dst = which == 0 ? q16 : (which == 1 ? k16 : v16);
#pragma unroll
  for (int nt = 0; nt < 4; ++nt) {
    int o  = bx * 128 + wn * 64 + nt * 16 + l15;
    int oo = o & 1023;
    int hh = oo >> 6, dd = oo & 63;
    int m2 = hh & 1;                   // mb%2 == hh%2 (16 even)
    float bsv = bias[oo];
#pragma unroll
    for (int mt = 0; mt < 4; ++mt) {
#pragma unroll
      for (int r = 0; r < 4; ++r) {
        int srow = by * 128 + wm * 64 + mt * 16 + quad * 4 + r;
        int b2 = srow >> 12, s = srow & 4095;
        float mv = 1.f + am[m2 * 4096 + s] * 1e-4f;
        float v = (acc[mt][nt][r] + bsv) * mv;
        int mb = b2 * 16 + hh;
        dst[((size_t)mb * 4096 + s) * 64 + dd] = (_Float16)v;
      }
    }
  }
}

// ---------------- fused: side GEMM (blocks<256) | V prep (blocks>=256) ----------------
// side: fp16x3 error-compensated sideQK(512x2048) = hbar @ [wq;wk]^T
// vprep: per-wave V block transpose (d-major) + block means
__global__ __launch_bounds__(256) void k_sidev(const _Float16* __restrict__ Ahi,
                                               const _Float16* __restrict__ Alo,
                                               const _Float16* __restrict__ Bhi,
                                               const _Float16* __restrict__ Blo,
                                               float* __restrict__ sideQK,
                                               const _Float16* __restrict__ v16,
                                               const float* __restrict__ tcv,
                                               float* __restrict__ vhat,
                                               _Float16* __restrict__ v16T) {
  __shared__ _Float16 smem[4 * 64 * 64];   // 32 KB overlay (side: 4 tiles; vprep: 4x Vs)
  const int tid = threadIdx.x;
  const int lane = tid & 63, wv = tid >> 6;

  if (blockIdx.x >= 256) {
    // ---- vprep: one wave per (mb, blk) ----
    _Float16* Vs = &smem[wv * 2304];       // 32*72
    int bid = (blockIdx.x - 256) * 4 + wv; // 0..4095
    int mb = bid >> 7, blk = bid & 127;
    const _Float16* src = v16 + ((size_t)mb * 4096 + blk * 32) * 64;
    int r = lane >> 3, c = (lane & 7) * 8;
#pragma unroll
    for (int it = 0; it < 4; ++it)
      *(uint4*)&Vs[(it * 8 + r) * 72 + c] = *(const uint4*)&src[(it * 8 + r) * 64 + c];
    __syncthreads();
    float acc = 0.f;
    half8 col[4];
#pragma unroll
    for (int k = 0; k < 32; ++k) {
      _Float16 x = Vs[k * 72 + lane];
      col[k >> 3][k & 7] = x;
      acc += (float)x;
    }
    vhat[(size_t)bid * 64 + lane] = acc / (tcv[(mb & 1) * 128 + blk] + 1e-6f);
    _Float16* dst = v16T + (size_t)(mb * 64 + lane) * 4096 + blk * 32;
#pragma unroll
    for (int p = 0; p < 4; ++p) *(half8*)&dst[p * 8] = col[p];
    return;
  }

  // ---- side GEMM ----
  const int bx = blockIdx.x & 31;   // 0..31 (N/64)
  const int by = blockIdx.x >> 5;   // 0..7  (M/64)
  const int wm = wv >> 1, wn = wv & 1;
  const int l15 = lane & 15, quad = lane >> 4;
  _Float16* sAhi = smem;
  _Float16* sAlo = smem + 4096;
  _Float16* sBhi = smem + 8192;
  _Float16* sBlo = smem + 12288;

  floatx4 acc[2][2] = {};

  const int srow = lane >> 3;
  const int scol = (((lane & 7) ^ (srow & 7)) * 8);
  const int swz  = l15 & 7;
  const _Float16* src;
  _Float16* dst;
  if      (wv == 0) { src = Ahi + (size_t)(by * 64) * 1024; dst = sAhi; }
  else if (wv == 1) { src = Alo + (size_t)(by * 64) * 1024; dst = sAlo; }
  else if (wv == 2) { src = Bhi + (size_t)(bx * 64) * 1024; dst = sBhi; }
  else              { src = Blo + (size_t)(bx * 64) * 1024; dst = sBlo; }

  for (int k0 = 0; k0 < 1024; k0 += 64) {
    __syncthreads();
#pragma unroll
    for (int i = 0; i < 8; ++i)
      load_lds16(src + (size_t)(i * 8 + srow) * 1024 + k0 + scol, dst + i * 512);
    __syncthreads();
#pragma unroll
    for (int ks = 0; ks < 2; ++ks) {
      const int kc = ks * 4;
      half8 ah[2], al[2], bh[2], bl[2];
#pragma unroll
      for (int mt = 0; mt < 2; ++mt) {
        int off = (wm * 32 + mt * 16 + l15) * 64 + (((kc + quad) ^ swz) << 3);
        ah[mt] = *(const half8*)&sAhi[off];
        al[mt] = *(const half8*)&sAlo[off];
      }
#pragma unroll
      for (int nt = 0; nt < 2; ++nt) {
        int off = (wn * 32 + nt * 16 + l15) * 64 + (((kc + quad) ^ swz) << 3);
        bh[nt] = *(const half8*)&sBhi[off];
        bl[nt] = *(const half8*)&sBlo[off];
      }
#pragma unroll
      for (int mt = 0; mt < 2; ++mt)
#pragma unroll
        for (int nt = 0; nt < 2; ++nt) {
          acc[mt][nt] = __builtin_amdgcn_mfma_f32_16x16x32_f16(ah[mt], bh[nt], acc[mt][nt], 0, 0, 0);
          acc[mt][nt] = __builtin_amdgcn_mfma_f32_16x16x32_f16(ah[mt], bl[nt], acc[mt][nt], 0, 0, 0);
          acc[mt][nt] = __builtin_amdgcn_mfma_f32_16x16x32_f16(al[mt], bh[nt], acc[mt][nt], 0, 0, 0);
        }
    }
  }
#pragma unroll
  for (int mt = 0; mt < 2; ++mt)
#pragma unroll
    for (int nt = 0; nt < 2; ++nt)
#pragma unroll
      for (int rr = 0; rr < 4; ++rr) {
        int row = by * 64 + wm * 32 + mt * 16 + quad * 4 + rr;
        int col = bx * 64 + wn * 32 + nt * 16 + l15;
        sideQK[(size_t)row * 2048 + col] = acc[mt][nt][rr];
      }
}

// ---------------- low-resolution logits + row max (conflict-free, rotated d) ----------
__global__ __launch_bounds__(256) void k_lowlogit(const float* __restrict__ sideQK,
                                                  const float* __restrict__ tcv,
                                                  const float* __restrict__ bq,
                                                  const float* __restrict__ bk,
                                                  float* __restrict__ ll,
                                                  float* __restrict__ rmaxout) {
  const int mb = blockIdx.x;
  const int ib = blockIdx.y;       // 0..7 : rows ib*16..+16
  const int b2 = mb >> 4, m2 = mb & 1, hh = mb & 15;
  const int combo = b2 * 2 + m2;
  const int tid = threadIdx.x;
  __shared__ float Kh[128 * 64];
  __shared__ float Qh[16 * 64];
  __shared__ float tcL[128];

  if (tid < 128) tcL[tid] = tcv[m2 * 128 + tid];
  __syncthreads();
#pragma unroll
  for (int i = 0; i < 8; ++i) {
    int ci = tid + i * 256;
    int row = ci >> 4, c4 = (ci & 15) * 4;
    float tck = tcL[row];
    float den = 1.f / (tck + 1e-6f);
    float4 x  = *(const float4*)&sideQK[((size_t)combo * 128 + row) * 2048 + 1024 + hh * 64 + c4];
    float4 bb = *(const float4*)&bk[hh * 64 + c4];
    float4 o;
    o.x = (x.x + bb.x * tck) * den; o.y = (x.y + bb.y * tck) * den;
    o.z = (x.z + bb.z * tck) * den; o.w = (x.w + bb.w * tck) * den;
    *(float4*)&Kh[row * 64 + c4] = o;
  }
  {
    int row = tid >> 4, c4 = (tid & 15) * 4;
    int gi = ib * 16 + row;
    float tcq = tcL[gi];
    float den = 1.f / (tcq + 1e-6f);
    float4 x  = *(const float4*)&sideQK[((size_t)combo * 128 + gi) * 2048 + hh * 64 + c4];
    float4 bb = *(const float4*)&bq[hh * 64 + c4];
    float4 o;
    o.x = (x.x + bb.x * tcq) * den; o.y = (x.y + bb.y * tcq) * den;
    o.z = (x.z + bb.z * tcq) * den; o.w = (x.w + bb.w * tcq) * den;
    *(float4*)&Qh[row * 64 + c4] = o;
  }
  __syncthreads();

  const int il = tid >> 4, jg = tid & 15;
  const int i = ib * 16 + il;
  float tcq = tcL[i];
  float dots[8] = {};
#pragma unroll
  for (int dd = 0; dd < 16; ++dd) {
    int d4 = ((dd + tid) & 15) * 4;       // lane-rotated: conflict-free LDS columns
    float4 qv = *(const float4*)&Qh[il * 64 + d4];
#pragma unroll
    for (int jj = 0; jj < 8; ++jj) {
      float4 kv = *(const float4*)&Kh[(jg * 8 + jj) * 64 + d4];
      dots[jj] += qv.x * kv.x + qv.y * kv.y + qv.z * kv.z + qv.w * kv.w;
    }
  }
  float tmax = -1e30f;
#pragma unroll
  for (int jj = 0; jj < 8; ++jj) {
    int j = jg * 8 + jj;
    float raw = dots[jj] * 0.125f;
    tmax = fmaxf(tmax, raw);
    float pen = (tcq * tcL[j] < 0.5f) ? 10000.f : 0.f;
    ll[(size_t)mb * 16384 + (size_t)i * 128 + j] = raw - pen;
  }
#pragma unroll
  for (int mk = 1; mk < 16; mk <<= 1) tmax = fmaxf(tmax, __shfl_xor(tmax, mk));
  if (jg == 0) rmaxout[mb * 128 + i] = tmax;
}

// ---------------- exact top-512 threshold + selected-block buckets --------------------
__global__ __launch_bounds__(256) void k_topk(const float* __restrict__ ll,
                                              const float* __restrict__ rmax,
                                              float* __restrict__ thr,
                                              int* __restrict__ selcnt,
                                              int* __restrict__ selkb) {
  const int mb = blockIdx.x;
  const int t = threadIdx.x;
  const int wid = t >> 6;
  __shared__ int red2[2][4];

  unsigned code[64];
#pragma unroll
  for (int j = 0; j < 64; ++j) {
    int e = j * 256 + t;
    int i = e >> 7, jj = e & 127;
    float lrn = ll[(size_t)mb * 16384 + e] - rmax[mb * 128 + i];
    int di = i - jj;
    if (di <= 1 && di >= -1) lrn += 5000.f;
    unsigned b = __float_as_uint(lrn);
    code[j] = (b & 0x80000000u) ? ~b : (b | 0x80000000u);
  }

  unsigned lo = 0u, hi = 0xFFFFFFFFu;
  for (int it = 0; it < 32; ++it) {
    unsigned mid = lo + ((hi - lo) >> 1);
    int c = 0;
#pragma unroll
    for (int j = 0; j < 64; ++j) c += (code[j] >= mid) ? 1 : 0;
#pragma unroll
    for (int mk = 1; mk < 64; mk <<= 1) c += __shfl_xor(c, mk);
    if ((t & 63) == 0) red2[it & 1][wid] = c;
    __syncthreads();
    int total = red2[it & 1][0] + red2[it & 1][1] + red2[it & 1][2] + red2[it & 1][3];
    if (total >= 512) lo = mid; else hi = mid;
  }
  if (t == 0) {
    unsigned bits = (lo & 0x80000000u) ? (lo & 0x7FFFFFFFu) : ~lo;
    thr[mb] = __uint_as_float(bits);
  }
#pragma unroll
  for (int j = 0; j < 64; ++j) {
    if (code[j] >= lo) {
      int e = j * 256 + t;
      int i = e >> 7, jj = e & 127;
      int slot = atomicAdd(&selcnt[mb * 128 + i], 1);
      if (slot < MAXSEL) selkb[(size_t)(mb * 128 + i) * MAXSEL + slot] = jj;
    }
  }
}

// ---------------- hi branch (online softmax, MFMA-norm) + low branch + combine --------
// 1 wave per (mb, query block). All fragment temporaries use compile-time indices ONLY
// (runtime-indexed register arrays lower to scratch on AMDGPU — R3's 20x regression).
__global__ __launch_bounds__(64) void k_hi(const _Float16* __restrict__ q16,
                                           const _Float16* __restrict__ k16,
                                           const _Float16* __restrict__ v16T,
                                           const int* __restrict__ selcnt,
                                           const int* __restrict__ selkb,
                                           const float* __restrict__ rmax,
                                           const float* __restrict__ thr,
                                           const float* __restrict__ tcv,
                                           const float* __restrict__ vhat,
                                           const float* __restrict__ ll,
                                           const float* __restrict__ am,
                                           float* __restrict__ out) {
  const int bid = blockIdx.x;
  const int mb = bid >> 7, qb = bid & 127;
  const int lane = threadIdx.x;
  const int l15 = lane & 15, quad = lane >> 4;
  const int m2 = mb & 1, b2 = mb >> 4, hh = mb & 15;

  __shared__ _Float16 Ps[32 * 40];

  const _Float16* qbase = q16 + ((size_t)mb * 4096 + qb * 32) * 64;
  half8 aq[2][2];
#pragma unroll
  for (int mt = 0; mt < 2; ++mt)
#pragma unroll
    for (int ks = 0; ks < 2; ++ks)
      aq[mt][ks] = *(const half8*)&qbase[(mt * 16 + l15) * 64 + ks * 32 + quad * 8];

  // ---- low branch (block-level; same for all 32 q rows). lane = dim ----
  const float rmaxb = rmax[bid];
  const float th = thr[mb];
  float accL = 0.f, nrmL = 0.f;
#pragma unroll 4
  for (int j = 0; j < 128; ++j) {
    float llv = ll[(size_t)mb * 16384 + (size_t)qb * 128 + j];
    float lrn = llv - rmaxb;
    int di = qb - j;
    if (di <= 1 && di >= -1) lrn += 5000.f;
    float w = (lrn >= th) ? 0.f : __expf(llv - rmaxb) * tcv[m2 * 128 + j];
    accL += w * vhat[((size_t)(mb * 128 + j)) * 64 + lane];
    nrmL += w;
  }

  int nk = selcnt[bid];
  if (nk > MAXSEL) nk = MAXSEL;
  const int* list = selkb + (size_t)bid * MAXSEL;

  const _Float16* kbase  = k16  + (size_t)mb * 4096 * 64;
  const _Float16* vtbase = v16T + (size_t)mb * 64 * 4096;

  float rm[2][4];
  floatx4 o[2][4] = {};
  floatx4 onrm[2] = {};
#pragma unroll
  for (int mt = 0; mt < 2; ++mt)
#pragma unroll
    for (int r = 0; r < 4; ++r) rm[mt][r] = -1e8f;

  half8 ones;
#pragma unroll
  for (int j = 0; j < 8; ++j) ones[j] = (_Float16)1.f;

  for (int t = 0; t < nk; ++t) {
    const int kb = list[t];
    const _Float16* kp = kbase + (size_t)kb * 32 * 64;
    half8 b0[2], b1[2];
#pragma unroll
    for (int ks = 0; ks < 2; ++ks) {
      b0[ks] = *(const half8*)&kp[(l15) * 64 + ks * 32 + quad * 8];
      b1[ks] = *(const half8*)&kp[(16 + l15) * 64 + ks * 32 + quad * 8];
    }
    // V fragments issued early: latency overlapped with QK-MFMA + softmax below
    const _Float16* vp = vtbase + kb * 32 + quad * 8;
    half8 vb0 = *(const half8*)&vp[(size_t)(l15) * 4096];
    half8 vb1 = *(const half8*)&vp[(size_t)(16 + l15) * 4096];
    half8 vb2 = *(const half8*)&vp[(size_t)(32 + l15) * 4096];
    half8 vb3 = *(const half8*)&vp[(size_t)(48 + l15) * 4096];

    floatx4 sf[2][2] = {};
    sf[0][0] = __builtin_amdgcn_mfma_f32_16x16x32_f16(aq[0][0], b0[0], sf[0][0], 0, 0, 0);
    sf[0][0] = __builtin_amdgcn_mfma_f32_16x16x32_f16(aq[0][1], b0[1], sf[0][0], 0, 0, 0);
    sf[0][1] = __builtin_amdgcn_mfma_f32_16x16x32_f16(aq[0][0], b1[0], sf[0][1], 0, 0, 0);
    sf[0][1] = __builtin_amdgcn_mfma_f32_16x16x32_f16(aq[0][1], b1[1], sf[0][1], 0, 0, 0);
    sf[1][0] = __builtin_amdgcn_mfma_f32_16x16x32_f16(aq[1][0], b0[0], sf[1][0], 0, 0, 0);
    sf[1][0] = __builtin_amdgcn_mfma_f32_16x16x32_f16(aq[1][1], b0[1], sf[1][0], 0, 0, 0);
    sf[1][1] = __builtin_amdgcn_mfma_f32_16x16x32_f16(aq[1][0], b1[0], sf[1][1], 0, 0, 0);
    sf[1][1] = __builtin_amdgcn_mfma_f32_16x16x32_f16(aq[1][1], b1[1], sf[1][1], 0, 0, 0);

    float pen0, pen1;
    {
      float mk0 = 1.f + am[m2 * 4096 + kb * 32 + l15] * 1e-4f;
      float mk1 = 1.f + am[m2 * 4096 + kb * 32 + 16 + l15] * 1e-4f;
      pen0 = 10000.f * (1.f - mk0);
      pen1 = 10000.f * (1.f - mk1);
    }
#pragma unroll
    for (int mt = 0; mt < 2; ++mt)
#pragma unroll
      for (int r = 0; r < 4; ++r) {
        float s0 = sf[mt][0][r] * 0.125f;
        float s1 = sf[mt][1][r] * 0.125f;
        float v = fmaxf(s0, s1);
#pragma unroll
        for (int mk = 1; mk < 16; mk <<= 1) v = fmaxf(v, __shfl_xor(v, mk));
        float mnew  = fmaxf(rm[mt][r], v);
        float alpha = __expf(rm[mt][r] - mnew);
        rm[mt][r] = mnew;
        float p0 = __expf(s0 - mnew - pen0);
        float p1 = __expf(s1 - mnew - pen1);
        o[mt][0][r] *= alpha; o[mt][1][r] *= alpha;
        o[mt][2][r] *= alpha; o[mt][3][r] *= alpha;
        onrm[mt][r] *= alpha;
        int row = mt * 16 + quad * 4 + r;
        Ps[row * 40 + l15] = (_Float16)p0;
        Ps[row * 40 + 16 + l15] = (_Float16)p1;
      }
    __syncthreads();
    half8 pa0 = *(const half8*)&Ps[(l15) * 40 + quad * 8];
    half8 pa1 = *(const half8*)&Ps[(16 + l15) * 40 + quad * 8];
    o[0][0] = __builtin_amdgcn_mfma_f32_16x16x32_f16(pa0, vb0, o[0][0], 0, 0, 0);
    o[0][1] = __builtin_amdgcn_mfma_f32_16x16x32_f16(pa0, vb1, o[0][1], 0, 0, 0);
    o[0][2] = __builtin_amdgcn_mfma_f32_16x16x32_f16(pa0, vb2, o[0][2], 0, 0, 0);
    o[0][3] = __builtin_amdgcn_mfma_f32_16x16x32_f16(pa0, vb3, o[0][3], 0, 0, 0);
    o[1][0] = __builtin_amdgcn_mfma_f32_16x16x32_f16(pa1, vb0, o[1][0], 0, 0, 0);
    o[1][1] = __builtin_amdgcn_mfma_f32_16x16x32_f16(pa1, vb1, o[1][1], 0, 0, 0);
    o[1][2] = __builtin_amdgcn_mfma_f32_16x16x32_f16(pa1, vb2, o[1][2], 0, 0, 0);
    o[1][3] = __builtin_amdgcn_mfma_f32_16x16x32_f16(pa1, vb3, o[1][3], 0, 0, 0);
    onrm[0] = __builtin_amdgcn_mfma_f32_16x16x32_f16(pa0, ones, onrm[0], 0, 0, 0);
    onrm[1] = __builtin_amdgcn_mfma_f32_16x16x32_f16(pa1, ones, onrm[1], 0, 0, 0);
    __syncthreads();
  }

  // ---- combine with low branch and write output ----
  float lo_d[4];
#pragma unroll
  for (int ntd = 0; ntd < 4; ++ntd) lo_d[ntd] = __shfl(accL, ntd * 16 + l15);
#pragma unroll
  for (int mt = 0; mt < 2; ++mt) {
#pragma unroll
    for (int r = 0; r < 4; ++r) {
      int q = mt * 16 + quad * 4 + r;
      int qpos = qb * 32 + q;
      float mq = 1.f + am[m2 * 4096 + qpos] * 1e-4f;
      float logc = (rmaxb - rm[mt][r]) * mq;
      float lc = __expf(fminf(logc, 0.f));
      float hc = __expf(-fmaxf(logc, 0.f));
      float den = onrm[mt][r] * hc + nrmL * lc + 1e-6f;
      float sc = mq / den;
#pragma unroll
      for (int ntd = 0; ntd < 4; ++ntd) {
        float val = (o[mt][ntd][r] * hc + lo_d[ntd] * lc) * sc;
        out[((size_t)b2 * 4096 + qpos) * 1024 + hh * 64 + ntd * 16 + l15] = val;
      }
    }
  }
}

// ---------------- host launch ----------------
extern "C" void kernel_launch(void* const* d_in, const int* in_sizes, int n_in,
                              void* d_out, int out_size, void* d_ws, size_t ws_size,
                              hipStream_t stream) {
  const float* hidden = (const float*)d_in[0];
  const float* am     = (const float*)d_in[1];
  const float* wq     = (const float*)d_in[2];
  const float* bq     = (const float*)d_in[3];
  const float* wk     = (const float*)d_in[4];
  const float* bk     = (const float*)d_in[5];
  const float* wv     = (const float*)d_in[6];
  const float* bv     = (const float*)d_in[7];
  float* out = (float*)d_out;

  char* ws = (char*)d_ws;
  size_t off = 0;
  auto alloc = [&](size_t bytes) -> char* {
    char* p = ws + off;
    off += (bytes + 255) & ~(size_t)255;
    return p;
  };
  _Float16* h16    = (_Float16*)alloc((size_t)M8 * H * 2);      // aliased by v16T later
  _Float16* w16    = (_Float16*)alloc((size_t)N3 * H * 2);
  _Float16* wlo    = (_Float16*)alloc((size_t)2 * H * H * 2);
  _Float16* q16    = (_Float16*)alloc((size_t)MBH * S * DH * 2);
  _Float16* k16    = (_Float16*)alloc((size_t)MBH * S * DH * 2);
  _Float16* v16    = (_Float16*)alloc((size_t)MBH * S * DH * 2);
  _Float16* hb_hi  = (_Float16*)alloc((size_t)4 * NB * H * 2);
  _Float16* hb_lo  = (_Float16*)alloc((size_t)4 * NB * H * 2);
  float* tcv       = (float*)alloc((size_t)2 * NB * 4);
  float* sideQK    = (float*)alloc((size_t)4 * NB * 2048 * 4);
  float* ll        = (float*)alloc((size_t)MBH * NB * NB * 4);
  float* rmax      = (float*)alloc((size_t)MBH * NB * 4);
  float* thr       = (float*)alloc((size_t)MBH * 4);
  int*   selcnt    = (int*)alloc((size_t)MBH * NB * 4);
  int*   selkb     = (int*)alloc((size_t)MBH * NB * MAXSEL * 4);
  float* vhat      = (float*)alloc((size_t)MBH * NB * DH * 4);
  _Float16* v16T   = h16;   // h16 dead after k_gemm_qkv; same element count (8.4M)

  k_prep<<<dim3(3328), dim3(256), 0, stream>>>(hidden, am, wq, wk, wv,
                                               h16, w16, wlo, hb_hi, hb_lo, tcv, selcnt);
  k_gemm_qkv<<<dim3(24, 64), dim3(256), 0, stream>>>(h16, w16, bq, bk, bv, am,
                                                     q16, k16, v16);
  k_sidev<<<dim3(256 + 1024), dim3(256), 0, stream>>>(hb_hi, hb_lo, w16, wlo, sideQK,
                                                      v16, tcv, vhat, v16T);
  k_lowlogit<<<dim3(32, 8), dim3(256), 0, stream>>>(sideQK, tcv, bq, bk, ll, rmax);
  k_topk<<<dim3(32), dim3(256), 0, stream>>>(ll, rmax, thr, selcnt, selkb);
  k_hi<<<dim3(4096), dim3(64), 0, stream>>>(q16, k16, v16T, selcnt, selkb, rmax, thr,
                                            tcv, vhat, ll, am, out);
}

// Round 6
// 304.309 us; speedup vs baseline: 6.1692x; 1.0484x over previous
//
#include <hip/hip_runtime.h>
#include <cstdint>
#include <cstddef>

// ---------------- constants ----------------
#define MAXSEL 160
static constexpr int S    = 4096;
static constexpr int H    = 1024;
static constexpr int DH   = 64;
static constexpr int NB   = 128;   // seq blocks (4096/32)
static constexpr int MBH  = 32;    // b*h = 2*16
static constexpr int M8   = 8192;  // 2*4096 rows
static constexpr int N3   = 3072;  // q|k|v features

typedef _Float16 half8 __attribute__((ext_vector_type(8)));
typedef _Float16 half4v __attribute__((ext_vector_type(4)));
typedef float floatx4 __attribute__((ext_vector_type(4)));

__device__ __forceinline__ void load_lds16(const void* g, void* l) {
  __builtin_amdgcn_global_load_lds((const __attribute__((address_space(1))) unsigned int*)g,
                                   (__attribute__((address_space(3))) unsigned int*)l,
                                   16, 0, 0);
}

// ---------------- fused prep: hbar + h16 cast | weight cast | selcnt zero -------------
__global__ __launch_bounds__(256) void k_prep(const float* __restrict__ hidden,
                                              const float* __restrict__ am,
                                              const float* __restrict__ wq,
                                              const float* __restrict__ wk,
                                              const float* __restrict__ wv,
                                              _Float16* __restrict__ h16,
                                              _Float16* __restrict__ w16,
                                              _Float16* __restrict__ wlo,
                                              _Float16* __restrict__ hb_hi,
                                              _Float16* __restrict__ hb_lo,
                                              float* __restrict__ tcv,
                                              int* __restrict__ selcnt) {
  const int blk_id = blockIdx.x;
  if (blk_id < 256) {
    if (blk_id == 0) {
      for (int i = threadIdx.x; i < MBH * NB; i += 256) selcnt[i] = 0;
    }
    int b2 = blk_id >> 7, blk = blk_id & 127;
    int c = threadIdx.x * 4;
    float4 s0 = make_float4(0.f, 0.f, 0.f, 0.f);
    float4 s1 = make_float4(0.f, 0.f, 0.f, 0.f);
    // unroll x4 with grouped loads for memory-level parallelism (R5: latency-bound)
    for (int i = 0; i < 32; i += 4) {
      int pos0 = blk * 32 + i;
      size_t base = ((size_t)b2 * 4096 + pos0) * 1024 + c;
      const float4 x0 = *(const float4*)&hidden[base];
      const float4 x1 = *(const float4*)&hidden[base + 1024];
      const float4 x2 = *(const float4*)&hidden[base + 2048];
      const float4 x3 = *(const float4*)&hidden[base + 3072];
      float a00 = am[pos0],      a01 = am[pos0 + 1],      a02 = am[pos0 + 2],      a03 = am[pos0 + 3];
      float a10 = am[4096+pos0], a11 = am[4096+pos0 + 1], a12 = am[4096+pos0 + 2], a13 = am[4096+pos0 + 3];
      half4v h;
      h[0]=(_Float16)x0.x; h[1]=(_Float16)x0.y; h[2]=(_Float16)x0.z; h[3]=(_Float16)x0.w;
      *(half4v*)&h16[base] = h;
      h[0]=(_Float16)x1.x; h[1]=(_Float16)x1.y; h[2]=(_Float16)x1.z; h[3]=(_Float16)x1.w;
      *(half4v*)&h16[base + 1024] = h;
      h[0]=(_Float16)x2.x; h[1]=(_Float16)x2.y; h[2]=(_Float16)x2.z; h[3]=(_Float16)x2.w;
      *(half4v*)&h16[base + 2048] = h;
      h[0]=(_Float16)x3.x; h[1]=(_Float16)x3.y; h[2]=(_Float16)x3.z; h[3]=(_Float16)x3.w;
      *(half4v*)&h16[base + 3072] = h;
      float m0, m1;
      m0 = 1.f + a00 * 1e-4f; m1 = 1.f + a10 * 1e-4f;
      s0.x += m0*x0.x; s0.y += m0*x0.y; s0.z += m0*x0.z; s0.w += m0*x0.w;
      s1.x += m1*x0.x; s1.y += m1*x0.y; s1.z += m1*x0.z; s1.w += m1*x0.w;
      m0 = 1.f + a01 * 1e-4f; m1 = 1.f + a11 * 1e-4f;
      s0.x += m0*x1.x; s0.y += m0*x1.y; s0.z += m0*x1.z; s0.w += m0*x1.w;
      s1.x += m1*x1.x; s1.y += m1*x1.y; s1.z += m1*x1.z; s1.w += m1*x1.w;
      m0 = 1.f + a02 * 1e-4f; m1 = 1.f + a12 * 1e-4f;
      s0.x += m0*x2.x; s0.y += m0*x2.y; s0.z += m0*x2.z; s0.w += m0*x2.w;
      s1.x += m1*x2.x; s1.y += m1*x2.y; s1.z += m1*x2.z; s1.w += m1*x2.w;
      m0 = 1.f + a03 * 1e-4f; m1 = 1.f + a13 * 1e-4f;
      s0.x += m0*x3.x; s0.y += m0*x3.y; s0.z += m0*x3.z; s0.w += m0*x3.w;
      s1.x += m1*x3.x; s1.y += m1*x3.y; s1.z += m1*x3.z; s1.w += m1*x3.w;
    }
    size_t row0 = (size_t)(b2 * 2 + 0) * 128 + blk;
    size_t row1 = (size_t)(b2 * 2 + 1) * 128 + blk;
    half4v hi, lo;
    hi[0]=(_Float16)s0.x; lo[0]=(_Float16)(s0.x-(float)hi[0]);
    hi[1]=(_Float16)s0.y; lo[1]=(_Float16)(s0.y-(float)hi[1]);
    hi[2]=(_Float16)s0.z; lo[2]=(_Float16)(s0.z-(float)hi[2]);
    hi[3]=(_Float16)s0.w; lo[3]=(_Float16)(s0.w-(float)hi[3]);
    *(half4v*)&hb_hi[row0 * 1024 + c] = hi;
    *(half4v*)&hb_lo[row0 * 1024 + c] = lo;
    hi[0]=(_Float16)s1.x; lo[0]=(_Float16)(s1.x-(float)hi[0]);
    hi[1]=(_Float16)s1.y; lo[1]=(_Float16)(s1.y-(float)hi[1]);
    hi[2]=(_Float16)s1.z; lo[2]=(_Float16)(s1.z-(float)hi[2]);
    hi[3]=(_Float16)s1.w; lo[3]=(_Float16)(s1.w-(float)hi[3]);
    *(half4v*)&hb_hi[row1 * 1024 + c] = hi;
    *(half4v*)&hb_lo[row1 * 1024 + c] = lo;
    if (b2 == 0 && threadIdx.x == 0) {
      float t0 = 0.f, t1 = 0.f;
      for (int i = 0; i < 32; ++i) {
        int pos = blk * 32 + i;
        t0 += 1.f + am[pos] * 1e-4f;
        t1 += 1.f + am[4096 + pos] * 1e-4f;
      }
      tcv[blk] = t0; tcv[128 + blk] = t1;
    }
  } else {
    long j = (long)(blk_id - 256) * 256 + threadIdx.x;   // float4 index into weights
    const long NW4 = (long)H * H / 4;
    int which = (int)(j / NW4);
    long jj = j - (long)which * NW4;
    const float* src = which == 0 ? wq : (which == 1 ? wk : wv);
    float4 x = ((const float4*)src)[jj];
    half4v h;
    h[0] = (_Float16)x.x; h[1] = (_Float16)x.y;
    h[2] = (_Float16)x.z; h[3] = (_Float16)x.w;
    *(half4v*)&w16[j * 4] = h;
    if (which < 2) {
      half4v r;
      r[0] = (_Float16)(x.x - (float)h[0]);
      r[1] = (_Float16)(x.y - (float)h[1]);
      r[2] = (_Float16)(x.z - (float)h[2]);
      r[3] = (_Float16)(x.w - (float)h[3]);
      *(half4v*)&wlo[j * 4] = r;
    }
  }
}

// ---------------- main QKV projection (R2 form, VGPR 112): C = A @ W^T, fp16 MFMA -----
__global__ __launch_bounds__(256) void k_gemm_qkv(const _Float16* __restrict__ A,
                                                  const _Float16* __restrict__ B,
                                                  const float* __restrict__ bq,
                                                  const float* __restrict__ bk,
                                                  const float* __restrict__ bv,
                                                  const float* __restrict__ am,
                                                  _Float16* __restrict__ q16,
                                                  _Float16* __restrict__ k16,
                                                  _Float16* __restrict__ v16) {
  const int bx = blockIdx.x;           // N tile 0..23
  const int by = blockIdx.y;           // M tile 0..63
  const int tid = threadIdx.x;
  const int lane = tid & 63, wv = tid >> 6;
  const int wm = wv >> 1, wn = wv & 1;
  const int l15 = lane & 15, quad = lane >> 4;

  __shared__ _Float16 As[128 * 64];
  __shared__ _Float16 Bs[128 * 64];

  floatx4 acc[4][4] = {};

  const _Float16* Ag = A + (size_t)(by * 128) * 1024;
  const _Float16* Bg = B + (size_t)(bx * 128) * 1024;
  const int srow_l = lane >> 3;                              // 0..7
  const int scol   = (((lane & 7) ^ (srow_l & 7)) * 8);      // swizzled source chunk
  const int swz    = l15 & 7;

  for (int k0 = 0; k0 < 1024; k0 += 64) {
    __syncthreads();
#pragma unroll
    for (int i = 0; i < 4; ++i) {
      int rb = i * 32 + wv * 8;
      load_lds16(Ag + (size_t)(rb + srow_l) * 1024 + k0 + scol, &As[rb * 64]);
      load_lds16(Bg + (size_t)(rb + srow_l) * 1024 + k0 + scol, &Bs[rb * 64]);
    }
    __syncthreads();
#pragma unroll
    for (int ks = 0; ks < 2; ++ks) {
      const int kc = ks * 4;
      half8 a[4], b[4];
#pragma unroll
      for (int mt = 0; mt < 4; ++mt)
        a[mt] = *(const half8*)&As[(wm * 64 + mt * 16 + l15) * 64 + (((kc + quad) ^ swz) << 3)];
#pragma unroll
      for (int nt = 0; nt < 4; ++nt)
        b[nt] = *(const half8*)&Bs[(wn * 64 + nt * 16 + l15) * 64 + (((kc + quad) ^ swz) << 3)];
#pragma unroll
      for (int mt = 0; mt < 4; ++mt)
#pragma unroll
        for (int nt = 0; nt < 4; ++nt)
          acc[mt][nt] = __builtin_amdgcn_mfma_f32_16x16x32_f16(a[mt], b[nt], acc[mt][nt], 0, 0, 0);
    }
  }

  // epilogue: scatter to q16/k16/v16 in (mb, s, dd) layout, + bias, * mask
  const int which = (bx * 128) >> 10;  // uniform per CTA
  const float* bias = which == 0 ? bq : (which == 1 ? bk : bv);
  _Float16* dst = which == 0 ? q16 : (which == 1 ? k16 : v16);
#pragma unroll
  for (int nt = 0; nt < 4; ++nt) {
    int o  = bx * 128 + wn * 64 + nt * 16 + l15;
    int oo = o & 1023;
    int hh = oo >> 6, dd = oo & 63;
    int m2 = hh & 1;                   // mb%2 == hh%2 (16 even)
    float bsv = bias[oo];
#pragma unroll
    for (int mt = 0; mt < 4; ++mt) {
#pragma unroll
      for (int r = 0; r < 4; ++r) {
        int srow = by * 128 + wm * 64 + mt * 16 + quad * 4 + r;
        int b2 = srow >> 12, s = srow & 4095;
        float mv = 1.f + am[m2 * 4096 + s] * 1e-4f;
        float v = (acc[mt][nt][r] + bsv) * mv;
        int mb = b2 * 16 + hh;
        dst[((size_t)mb * 4096 + s) * 64 + dd] = (_Float16)v;
      }
    }
  }
}

// ---------------- fused: side GEMM split-K=2 (blocks<512) | V prep (blocks>=512) ------
// side: fp16x3 error-compensated partials sideQK[kk](512x2048) = hbar @ [wq;wk]^T (K-half)
// vprep: per-wave V block transpose (d-major) + block means
__global__ __launch_bounds__(256) void k_sidev(const _Float16* __restrict__ Ahi,
                                               const _Float16* __restrict__ Alo,
                                               const _Float16* __restrict__ Bhi,
                                               const _Float16* __restrict__ Blo,
                                               float* __restrict__ sideQK,
                                               const _Float16* __restrict__ v16,
                                               const float* __restrict__ tcv,
                                               float* __restrict__ vhat,
                                               _Float16* __restrict__ v16T) {
  __shared__ _Float16 smem[4 * 64 * 64];   // 32 KB overlay (side: 4 tiles; vprep: 4x Vs)
  const int tid = threadIdx.x;
  const int lane = tid & 63, wv = tid >> 6;

  if (blockIdx.x >= 512) {
    // ---- vprep: one wave per (mb, blk) ----
    _Float16* Vs = &smem[wv * 2304];       // 32*72
    int bid = (blockIdx.x - 512) * 4 + wv; // 0..4095
    int mb = bid >> 7, blk = bid & 127;
    const _Float16* src = v16 + ((size_t)mb * 4096 + blk * 32) * 64;
    int r = lane >> 3, c = (lane & 7) * 8;
#pragma unroll
    for (int it = 0; it < 4; ++it)
      *(uint4*)&Vs[(it * 8 + r) * 72 + c] = *(const uint4*)&src[(it * 8 + r) * 64 + c];
    __syncthreads();
    float acc = 0.f;
    half8 col[4];
#pragma unroll
    for (int k = 0; k < 32; ++k) {
      _Float16 x = Vs[k * 72 + lane];
      col[k >> 3][k & 7] = x;
      acc += (float)x;
    }
    vhat[(size_t)bid * 64 + lane] = acc / (tcv[(mb & 1) * 128 + blk] + 1e-6f);
    _Float16* dst = v16T + (size_t)(mb * 64 + lane) * 4096 + blk * 32;
#pragma unroll
    for (int p = 0; p < 4; ++p) *(half8*)&dst[p * 8] = col[p];
    return;
  }

  // ---- side GEMM (split-K: kk selects K-half) ----
  const int kk = blockIdx.x >> 8;          // 0 or 1
  const int bb = blockIdx.x & 255;
  const int bx = bb & 31;                  // 0..31 (N/64)
  const int by = bb >> 5;                  // 0..7  (M/64)
  const int wm = wv >> 1, wn = wv & 1;
  const int l15 = lane & 15, quad = lane >> 4;
  _Float16* sAhi = smem;
  _Float16* sAlo = smem + 4096;
  _Float16* sBhi = smem + 8192;
  _Float16* sBlo = smem + 12288;

  floatx4 acc[2][2] = {};

  const int srow = lane >> 3;
  const int scol = (((lane & 7) ^ (srow & 7)) * 8);
  const int swz  = l15 & 7;
  const _Float16* src;
  _Float16* dst;
  if      (wv == 0) { src = Ahi + (size_t)(by * 64) * 1024; dst = sAhi; }
  else if (wv == 1) { src = Alo + (size_t)(by * 64) * 1024; dst = sAlo; }
  else if (wv == 2) { src = Bhi + (size_t)(bx * 64) * 1024; dst = sBhi; }
  else              { src = Blo + (size_t)(bx * 64) * 1024; dst = sBlo; }

  const int kbeg = kk * 512;
  for (int k0 = kbeg; k0 < kbeg + 512; k0 += 64) {
    __syncthreads();
#pragma unroll
    for (int i = 0; i < 8; ++i)
      load_lds16(src + (size_t)(i * 8 + srow) * 1024 + k0 + scol, dst + i * 512);
    __syncthreads();
#pragma unroll
    for (int ks = 0; ks < 2; ++ks) {
      const int kc = ks * 4;
      half8 ah[2], al[2], bh[2], bl[2];
#pragma unroll
      for (int mt = 0; mt < 2; ++mt) {
        int off = (wm * 32 + mt * 16 + l15) * 64 + (((kc + quad) ^ swz) << 3);
        ah[mt] = *(const half8*)&sAhi[off];
        al[mt] = *(const half8*)&sAlo[off];
      }
#pragma unroll
      for (int nt = 0; nt < 2; ++nt) {
        int off = (wn * 32 + nt * 16 + l15) * 64 + (((kc + quad) ^ swz) << 3);
        bh[nt] = *(const half8*)&sBhi[off];
        bl[nt] = *(const half8*)&sBlo[off];
      }
#pragma unroll
      for (int mt = 0; mt < 2; ++mt)
#pragma unroll
        for (int nt = 0; nt < 2; ++nt) {
          acc[mt][nt] = __builtin_amdgcn_mfma_f32_16x16x32_f16(ah[mt], bh[nt], acc[mt][nt], 0, 0, 0);
          acc[mt][nt] = __builtin_amdgcn_mfma_f32_16x16x32_f16(ah[mt], bl[nt], acc[mt][nt], 0, 0, 0);
          acc[mt][nt] = __builtin_amdgcn_mfma_f32_16x16x32_f16(al[mt], bh[nt], acc[mt][nt], 0, 0, 0);
        }
    }
  }
  float* outp = sideQK + (size_t)kk * (512 * 2048);
#pragma unroll
  for (int mt = 0; mt < 2; ++mt)
#pragma unroll
    for (int nt = 0; nt < 2; ++nt)
#pragma unroll
      for (int rr = 0; rr < 4; ++rr) {
        int row = by * 64 + wm * 32 + mt * 16 + quad * 4 + rr;
        int col = bx * 64 + wn * 32 + nt * 16 + l15;
        outp[(size_t)row * 2048 + col] = acc[mt][nt][rr];
      }
}

// ---------------- low-resolution logits + row max (sums split-K partials) -------------
__global__ __launch_bounds__(256) void k_lowlogit(const float* __restrict__ sideQK,
                                                  const float* __restrict__ tcv,
                                                  const float* __restrict__ bq,
                                                  const float* __restrict__ bk,
                                                  float* __restrict__ ll,
                                                  float* __restrict__ rmaxout) {
  const int mb = blockIdx.x;
  const int ib = blockIdx.y;       // 0..7 : rows ib*16..+16
  const int b2 = mb >> 4, m2 = mb & 1, hh = mb & 15;
  const int combo = b2 * 2 + m2;
  const int tid = threadIdx.x;
  __shared__ float Kh[128 * 64];
  __shared__ float Qh[16 * 64];
  __shared__ float tcL[128];

  const float* P1 = sideQK + (size_t)512 * 2048;

  if (tid < 128) tcL[tid] = tcv[m2 * 128 + tid];
  __syncthreads();
#pragma unroll
  for (int i = 0; i < 8; ++i) {
    int ci = tid + i * 256;
    int row = ci >> 4, c4 = (ci & 15) * 4;
    float tck = tcL[row];
    float den = 1.f / (tck + 1e-6f);
    size_t idx = ((size_t)combo * 128 + row) * 2048 + 1024 + hh * 64 + c4;
    float4 x0 = *(const float4*)&sideQK[idx];
    float4 x1 = *(const float4*)&P1[idx];
    float4 bb = *(const float4*)&bk[hh * 64 + c4];
    float4 o;
    o.x = (x0.x + x1.x + bb.x * tck) * den; o.y = (x0.y + x1.y + bb.y * tck) * den;
    o.z = (x0.z + x1.z + bb.z * tck) * den; o.w = (x0.w + x1.w + bb.w * tck) * den;
    *(float4*)&Kh[row * 64 + c4] = o;
  }
  {
    int row = tid >> 4, c4 = (tid & 15) * 4;
    int gi = ib * 16 + row;
    float tcq = tcL[gi];
    float den = 1.f / (tcq + 1e-6f);
    size_t idx = ((size_t)combo * 128 + gi) * 2048 + hh * 64 + c4;
    float4 x0 = *(const float4*)&sideQK[idx];
    float4 x1 = *(const float4*)&P1[idx];
    float4 bb = *(const float4*)&bq[hh * 64 + c4];
    float4 o;
    o.x = (x0.x + x1.x + bb.x * tcq) * den; o.y = (x0.y + x1.y + bb.y * tcq) * den;
    o.z = (x0.z + x1.z + bb.z * tcq) * den; o.w = (x0.w + x1.w + bb.w * tcq) * den;
    *(float4*)&Qh[row * 64 + c4] = o;
  }
  __syncthreads();

  const int il = tid >> 4, jg = tid & 15;
  const int i = ib * 16 + il;
  float tcq = tcL[i];
  float dots[8] = {};
#pragma unroll
  for (int dd = 0; dd < 16; ++dd) {
    int d4 = ((dd + tid) & 15) * 4;       // lane-rotated: conflict-free LDS columns
    float4 qv = *(const float4*)&Qh[il * 64 + d4];
#pragma unroll
    for (int jj = 0; jj < 8; ++jj) {
      float4 kv = *(const float4*)&Kh[(jg * 8 + jj) * 64 + d4];
      dots[jj] += qv.x * kv.x + qv.y * kv.y + qv.z * kv.z + qv.w * kv.w;
    }
  }
  float tmax = -1e30f;
#pragma unroll
  for (int jj = 0; jj < 8; ++jj) {
    int j = jg * 8 + jj;
    float raw = dots[jj] * 0.125f;
    tmax = fmaxf(tmax, raw);
    float pen = (tcq * tcL[j] < 0.5f) ? 10000.f : 0.f;
    ll[(size_t)mb * 16384 + (size_t)i * 128 + j] = raw - pen;
  }
#pragma unroll
  for (int mk = 1; mk < 16; mk <<= 1) tmax = fmaxf(tmax, __shfl_xor(tmax, mk));
  if (jg == 0) rmaxout[mb * 128 + i] = tmax;
}

// ---------------- exact top-512 threshold + selected-block buckets --------------------
__global__ __launch_bounds__(256) void k_topk(const float* __restrict__ ll,
                                              const float* __restrict__ rmax,
                                              float* __restrict__ thr,
                                              int* __restrict__ selcnt,
                                              int* __restrict__ selkb) {
  const int mb = blockIdx.x;
  const int t = threadIdx.x;
  const int wid = t >> 6;
  __shared__ int red2[2][4];

  unsigned code[64];
#pragma unroll
  for (int j = 0; j < 64; ++j) {
    int e = j * 256 + t;
    int i = e >> 7, jj = e & 127;
    float lrn = ll[(size_t)mb * 16384 + e] - rmax[mb * 128 + i];
    int di = i - jj;
    if (di <= 1 && di >= -1) lrn += 5000.f;
    unsigned b = __float_as_uint(lrn);
    code[j] = (b & 0x80000000u) ? ~b : (b | 0x80000000u);
  }

  unsigned lo = 0u, hi = 0xFFFFFFFFu;
  for (int it = 0; it < 32; ++it) {
    unsigned mid = lo + ((hi - lo) >> 1);
    int c = 0;
#pragma unroll
    for (int j = 0; j < 64; ++j) c += (code[j] >= mid) ? 1 : 0;
#pragma unroll
    for (int mk = 1; mk < 64; mk <<= 1) c += __shfl_xor(c, mk);
    if ((t & 63) == 0) red2[it & 1][wid] = c;
    __syncthreads();
    int total = red2[it & 1][0] + red2[it & 1][1] + red2[it & 1][2] + red2[it & 1][3];
    if (total >= 512) lo = mid; else hi = mid;
  }
  if (t == 0) {
    unsigned bits = (lo & 0x80000000u) ? (lo & 0x7FFFFFFFu) : ~lo;
    thr[mb] = __uint_as_float(bits);
  }
#pragma unroll
  for (int j = 0; j < 64; ++j) {
    if (code[j] >= lo) {
      int e = j * 256 + t;
      int i = e >> 7, jj = e & 127;
      int slot = atomicAdd(&selcnt[mb * 128 + i], 1);
      if (slot < MAXSEL) selkb[(size_t)(mb * 128 + i) * MAXSEL + slot] = jj;
    }
  }
}

// ---------------- hi branch (online softmax, MFMA-norm) + low branch + combine --------
// 1 wave per (mb, query block). XCD-swizzled: mb = blockIdx & 31 -> blockIdx%8 = mb%8,
// so all 128 CTAs of one mb share one XCD's L2 (K+V+vhat working set ~1 MB/mb,
// 4 mb/XCD ~= 4 MB L2). Compile-time-indexed fragments only (R3 scratch lesson).
__global__ __launch_bounds__(64) void k_hi(const _Float16* __restrict__ q16,
                                           const _Float16* __restrict__ k16,
                                           const _Float16* __restrict__ v16T,
                                           const int* __restrict__ selcnt,
                                           const int* __restrict__ selkb,
                                           const float* __restrict__ rmax,
                                           const float* __restrict__ thr,
                                           const float* __restrict__ tcv,
                                           const float* __restrict__ vhat,
                                           const float* __restrict__ ll,
                                           const float* __restrict__ am,
                                           float* __restrict__ out) {
  const int mb = blockIdx.x & 31, qb = blockIdx.x >> 5;
  const int sid = mb * 128 + qb;
  const int lane = threadIdx.x;
  const int l15 = lane & 15, quad = lane >> 4;
  const int m2 = mb & 1, b2 = mb >> 4, hh = mb & 15;

  __shared__ _Float16 Ps[32 * 40];

  const _Float16* qbase = q16 + ((size_t)mb * 4096 + qb * 32) * 64;
  half8 aq[2][2];
#pragma unroll
  for (int mt = 0; mt < 2; ++mt)
#pragma unroll
    for (int ks = 0; ks < 2; ++ks)
      aq[mt][ks] = *(const half8*)&qbase[(mt * 16 + l15) * 64 + ks * 32 + quad * 8];

  // ---- low branch (block-level; same for all 32 q rows). lane = dim ----
  const float rmaxb = rmax[sid];
  const float th = thr[mb];
  float accL = 0.f, nrmL = 0.f;
#pragma unroll 4
  for (int j = 0; j < 128; ++j) {
    float llv = ll[(size_t)mb * 16384 + (size_t)qb * 128 + j];
    float lrn = llv - rmaxb;
    int di = qb - j;
    if (di <= 1 && di >= -1) lrn += 5000.f;
    float w = (lrn >= th) ? 0.f : __expf(llv - rmaxb) * tcv[m2 * 128 + j];
    accL += w * vhat[((size_t)(mb * 128 + j)) * 64 + lane];
    nrmL += w;
  }

  int nk = selcnt[sid];
  if (nk > MAXSEL) nk = MAXSEL;
  const int* list = selkb + (size_t)sid * MAXSEL;

  const _Float16* kbase  = k16  + (size_t)mb * 4096 * 64;
  const _Float16* vtbase = v16T + (size_t)mb * 64 * 4096;

  float rm[2][4];
  floatx4 o[2][4] = {};
  floatx4 onrm[2] = {};
#pragma unroll
  for (int mt = 0; mt < 2; ++mt)
#pragma unroll
    for (int r = 0; r < 4; ++r) rm[mt][r] = -1e8f;

  half8 ones;
#pragma unroll
  for (int j = 0; j < 8; ++j) ones[j] = (_Float16)1.f;

  for (int t = 0; t < nk; ++t) {
    const int kb = list[t];
    const _Float16* kp = kbase + (size_t)kb * 32 * 64;
    half8 b0[2], b1[2];
#pragma unroll
    for (int ks = 0; ks < 2; ++ks) {
      b0[ks] = *(const half8*)&kp[(l15) * 64 + ks * 32 + quad * 8];
      b1[ks] = *(const half8*)&kp[(16 + l15) * 64 + ks * 32 + quad * 8];
    }
    // V fragments issued early: latency overlapped with QK-MFMA + softmax below
    const _Float16* vp = vtbase + kb * 32 + quad * 8;
    half8 vb0 = *(const half8*)&vp[(size_t)(l15) * 4096];
    half8 vb1 = *(const half8*)&vp[(size_t)(16 + l15) * 4096];
    half8 vb2 = *(const half8*)&vp[(size_t)(32 + l15) * 4096];
    half8 vb3 = *(const half8*)&vp[(size_t)(48 + l15) * 4096];

    floatx4 sf[2][2] = {};
    sf[0][0] = __builtin_amdgcn_mfma_f32_16x16x32_f16(aq[0][0], b0[0], sf[0][0], 0, 0, 0);
    sf[0][0] = __builtin_amdgcn_mfma_f32_16x16x32_f16(aq[0][1], b0[1], sf[0][0], 0, 0, 0);
    sf[0][1] = __builtin_amdgcn_mfma_f32_16x16x32_f16(aq[0][0], b1[0], sf[0][1], 0, 0, 0);
    sf[0][1] = __builtin_amdgcn_mfma_f32_16x16x32_f16(aq[0][1], b1[1], sf[0][1], 0, 0, 0);
    sf[1][0] = __builtin_amdgcn_mfma_f32_16x16x32_f16(aq[1][0], b0[0], sf[1][0], 0, 0, 0);
    sf[1][0] = __builtin_amdgcn_mfma_f32_16x16x32_f16(aq[1][1], b0[1], sf[1][0], 0, 0, 0);
    sf[1][1] = __builtin_amdgcn_mfma_f32_16x16x32_f16(aq[1][0], b1[0], sf[1][1], 0, 0, 0);
    sf[1][1] = __builtin_amdgcn_mfma_f32_16x16x32_f16(aq[1][1], b1[1], sf[1][1], 0, 0, 0);

    float pen0, pen1;
    {
      float mk0 = 1.f + am[m2 * 4096 + kb * 32 + l15] * 1e-4f;
      float mk1 = 1.f + am[m2 * 4096 + kb * 32 + 16 + l15] * 1e-4f;
      pen0 = 10000.f * (1.f - mk0);
      pen1 = 10000.f * (1.f - mk1);
    }
#pragma unroll
    for (int mt = 0; mt < 2; ++mt)
#pragma unroll
      for (int r = 0; r < 4; ++r) {
        float s0 = sf[mt][0][r] * 0.125f;
        float s1 = sf[mt][1][r] * 0.125f;
        float v = fmaxf(s0, s1);
#pragma unroll
        for (int mk = 1; mk < 16; mk <<= 1) v = fmaxf(v, __shfl_xor(v, mk));
        float mnew  = fmaxf(rm[mt][r], v);
        float alpha = __expf(rm[mt][r] - mnew);
        rm[mt][r] = mnew;
        float p0 = __expf(s0 - mnew - pen0);
        float p1 = __expf(s1 - mnew - pen1);
        o[mt][0][r] *= alpha; o[mt][1][r] *= alpha;
        o[mt][2][r] *= alpha; o[mt][3][r] *= alpha;
        onrm[mt][r] *= alpha;
        int row = mt * 16 + quad * 4 + r;
        Ps[row * 40 + l15] = (_Float16)p0;
        Ps[row * 40 + 16 + l15] = (_Float16)p1;
      }
    __syncthreads();
    half8 pa0 = *(const half8*)&Ps[(l15) * 40 + quad * 8];
    half8 pa1 = *(const half8*)&Ps[(16 + l15) * 40 + quad * 8];
    o[0][0] = __builtin_amdgcn_mfma_f32_16x16x32_f16(pa0, vb0, o[0][0], 0, 0, 0);
    o[0][1] = __builtin_amdgcn_mfma_f32_16x16x32_f16(pa0, vb1, o[0][1], 0, 0, 0);
    o[0][2] = __builtin_amdgcn_mfma_f32_16x16x32_f16(pa0, vb2, o[0][2], 0, 0, 0);
    o[0][3] = __builtin_amdgcn_mfma_f32_16x16x32_f16(pa0, vb3, o[0][3], 0, 0, 0);
    o[1][0] = __builtin_amdgcn_mfma_f32_16x16x32_f16(pa1, vb0, o[1][0], 0, 0, 0);
    o[1][1] = __builtin_amdgcn_mfma_f32_16x16x32_f16(pa1, vb1, o[1][1], 0, 0, 0);
    o[1][2] = __builtin_amdgcn_mfma_f32_16x16x32_f16(pa1, vb2, o[1][2], 0, 0, 0);
    o[1][3] = __builtin_amdgcn_mfma_f32_16x16x32_f16(pa1, vb3, o[1][3], 0, 0, 0);
    onrm[0] = __builtin_amdgcn_mfma_f32_16x16x32_f16(pa0, ones, onrm[0], 0, 0, 0);
    onrm[1] = __builtin_amdgcn_mfma_f32_16x16x32_f16(pa1, ones, onrm[1], 0, 0, 0);
    __syncthreads();
  }

  // ---- combine with low branch and write output ----
  float lo_d[4];
#pragma unroll
  for (int ntd = 0; ntd < 4; ++ntd) lo_d[ntd] = __shfl(accL, ntd * 16 + l15);
#pragma unroll
  for (int mt = 0; mt < 2; ++mt) {
#pragma unroll
    for (int r = 0; r < 4; ++r) {
      int q = mt * 16 + quad * 4 + r;
      int qpos = qb * 32 + q;
      float mq = 1.f + am[m2 * 4096 + qpos] * 1e-4f;
      float logc = (rmaxb - rm[mt][r]) * mq;
      float lc = __expf(fminf(logc, 0.f));
      float hc = __expf(-fmaxf(logc, 0.f));
      float den = onrm[mt][r] * hc + nrmL * lc + 1e-6f;
      float sc = mq / den;
#pragma unroll
      for (int ntd = 0; ntd < 4; ++ntd) {
        float val = (o[mt][ntd][r] * hc + lo_d[ntd] * lc) * sc;
        out[((size_t)b2 * 4096 + qpos) * 1024 + hh * 64 + ntd * 16 + l15] = val;
      }
    }
  }
}

// ---------------- host launch ----------------
extern "C" void kernel_launch(void* const* d_in, const int* in_sizes, int n_in,
                              void* d_out, int out_size, void* d_ws, size_t ws_size,
                              hipStream_t stream) {
  const float* hidden = (const float*)d_in[0];
  const float* am     = (const float*)d_in[1];
  const float* wq     = (const float*)d_in[2];
  const float* bq     = (const float*)d_in[3];
  const float* wk     = (const float*)d_in[4];
  const float* bk     = (const float*)d_in[5];
  const float* wv     = (const float*)d_in[6];
  const float* bv     = (const float*)d_in[7];
  float* out = (float*)d_out;

  char* ws = (char*)d_ws;
  size_t off = 0;
  auto alloc = [&](size_t bytes) -> char* {
    char* p = ws + off;
    off += (bytes + 255) & ~(size_t)255;
    return p;
  };
  _Float16* h16    = (_Float16*)alloc((size_t)M8 * H * 2);      // aliased by v16T later
  _Float16* w16    = (_Float16*)alloc((size_t)N3 * H * 2);
  _Float16* wlo    = (_Float16*)alloc((size_t)2 * H * H * 2);
  _Float16* q16    = (_Float16*)alloc((size_t)MBH * S * DH * 2);
  _Float16* k16    = (_Float16*)alloc((size_t)MBH * S * DH * 2);
  _Float16* v16    = (_Float16*)alloc((size_t)MBH * S * DH * 2);
  _Float16* hb_hi  = (_Float16*)alloc((size_t)4 * NB * H * 2);
  _Float16* hb_lo  = (_Float16*)alloc((size_t)4 * NB * H * 2);
  float* tcv       = (float*)alloc((size_t)2 * NB * 4);
  float* sideQK    = (float*)alloc((size_t)2 * 512 * 2048 * 4);  // 2 split-K partials
  float* ll        = (float*)alloc((size_t)MBH * NB * NB * 4);
  float* rmax      = (float*)alloc((size_t)MBH * NB * 4);
  float* thr       = (float*)alloc((size_t)MBH * 4);
  int*   selcnt    = (int*)alloc((size_t)MBH * NB * 4);
  int*   selkb     = (int*)alloc((size_t)MBH * NB * MAXSEL * 4);
  float* vhat      = (float*)alloc((size_t)MBH * NB * DH * 4);
  _Float16* v16T   = h16;   // h16 dead after k_gemm_qkv; same element count (8.4M)

  k_prep<<<dim3(3328), dim3(256), 0, stream>>>(hidden, am, wq, wk, wv,
                                               h16, w16, wlo, hb_hi, hb_lo, tcv, selcnt);
  k_gemm_qkv<<<dim3(24, 64), dim3(256), 0, stream>>>(h16, w16, bq, bk, bv, am,
                                                     q16, k16, v16);
  k_sidev<<<dim3(512 + 1024), dim3(256), 0, stream>>>(hb_hi, hb_lo, w16, wlo, sideQK,
                                                      v16, tcv, vhat, v16T);
  k_lowlogit<<<dim3(32, 8), dim3(256), 0, stream>>>(sideQK, tcv, bq, bk, ll, rmax);
  k_topk<<<dim3(32), dim3(256), 0, stream>>>(ll, rmax, thr, selcnt, selkb);
  k_hi<<<dim3(4096), dim3(64), 0, stream>>>(q16, k16, v16T, selcnt, selkb, rmax, thr,
                                            tcv, vhat, ll, am, out);
}